// Round 8
// baseline (1261.764 us; speedup 1.0000x reference)
//
#include <hip/hip_runtime.h>
#include <stdint.h>

// MGCN pipeline, R8: f32 inputs/outputs (the reference dtypes — R3's "harness
// converted to bf16" inference was a traceback misread; R0-R7 evidence is
// fully consistent with f32 I/O + my bf16 output packing being the only bug).
// Internal compute: bf16 MFMA with f32 accum. adj lives f32 in d_out's A_norm
// slot and is normalized in place. ws ~= 57 MB.

typedef __attribute__((ext_vector_type(8))) short short8;
typedef __attribute__((ext_vector_type(4))) float floatx4;

__device__ __forceinline__ unsigned short f2bf(float f) {
    unsigned int x = __builtin_bit_cast(unsigned int, f);
    x += 0x7fffu + ((x >> 16) & 1u);   // RNE
    return (unsigned short)(x >> 16);
}
__device__ __forceinline__ float bf2f(unsigned short u) {
    return __builtin_bit_cast(float, (unsigned int)u << 16);
}

#define MODE_ATTR 0
#define MODE_ADJ  1
#define MODE_TX1  2
#define MODE_TX2  3
#define MODE_SALL 4

// ---------------------------------------------------------------------------
// Generic bt-GEMM: C[i][j] = sum_k A[i][k]*Bt[j][k], bf16 in, f32 accum.
// Block 256 thr = 4 waves in 2x2, each wave 64x64 (4x4 mfma tiles).
// ---------------------------------------------------------------------------
__global__ __launch_bounds__(256, 2)
void gemm_bt(const unsigned short* __restrict__ A, const unsigned short* __restrict__ Bt,
             int lda, int ldb, int K, int mode,
             float* __restrict__ fout, unsigned short* __restrict__ bout,
             unsigned short* __restrict__ bout2,
             const float* __restrict__ veci, const float* __restrict__ vecj,
             const float* __restrict__ xf32)
{
    __shared__ __attribute__((aligned(16))) unsigned short As[128 * 32];
    __shared__ __attribute__((aligned(16))) unsigned short Bs[128 * 32];
    const int t   = threadIdx.x;
    const int w   = t >> 6;
    const int m0  = blockIdx.y * 128;
    const int n0  = blockIdx.x * 128;
    const int q   = (t & 63) >> 4;
    const int m16 = t & 15;
    const int wm  = (w & 1) * 64;
    const int wn  = (w >> 1) * 64;

    floatx4 acc[4][4];
#pragma unroll
    for (int a = 0; a < 4; a++)
#pragma unroll
        for (int b = 0; b < 4; b++)
            acc[a][b] = (floatx4){0.f, 0.f, 0.f, 0.f};

    for (int k0 = 0; k0 < K; k0 += 32) {
        uint4 va[2], vb[2];
#pragma unroll
        for (int c = 0; c < 2; c++) {
            const int off  = (c * 256 + t) * 16;
            const int row  = off >> 6;
            const int colb = off & 63;
            va[c] = *(const uint4*)((const char*)(A + (size_t)(m0 + row) * lda + k0) + colb);
            vb[c] = *(const uint4*)((const char*)(Bt + (size_t)(n0 + row) * ldb + k0) + colb);
        }
        __syncthreads();   // prev iteration's LDS reads done
#pragma unroll
        for (int c = 0; c < 2; c++) {
            const int off = (c * 256 + t) * 16;
            *(uint4*)((char*)As + off) = va[c];
            *(uint4*)((char*)Bs + off) = vb[c];
        }
        __syncthreads();

        short8 af[4], bf[4];
#pragma unroll
        for (int mt = 0; mt < 4; mt++)
            af[mt] = *reinterpret_cast<const short8*>(&As[(wm + mt * 16 + m16) * 32 + q * 8]);
#pragma unroll
        for (int nt = 0; nt < 4; nt++)
            bf[nt] = *reinterpret_cast<const short8*>(&Bs[(wn + nt * 16 + m16) * 32 + q * 8]);
#pragma unroll
        for (int mt = 0; mt < 4; mt++)
#pragma unroll
            for (int nt = 0; nt < 4; nt++)
                acc[mt][nt] = __builtin_amdgcn_mfma_f32_16x16x32_bf16(af[mt], bf[nt], acc[mt][nt], 0, 0, 0);
    }

    // epilogue: C/D layout col = lane&15, row = q*4 + reg
#pragma unroll
    for (int mt = 0; mt < 4; mt++) {
#pragma unroll
        for (int nt = 0; nt < 4; nt++) {
#pragma unroll
            for (int r = 0; r < 4; r++) {
                const int i = m0 + wm + mt * 16 + q * 4 + r;
                const int j = n0 + wn + nt * 16 + m16;
                float v = acc[mt][nt][r];
                if (mode == MODE_ATTR) {
                    v += vecj[j];                     // gglb, f32
                    v = 1.0f / (1.0f + __expf(-v));
                    bout[(size_t)i * 4096 + j] = f2bf(v);
                } else if (mode == MODE_ADJ) {
                    fout[(size_t)i * 4096 + j] = v * veci[i] * vecj[j];   // f32 adj
                } else if (mode == MODE_TX1) {
                    if (j < 200) {
                        unsigned short b = f2bf(v);
                        bout[(size_t)i * 608 + 200 + j] = b;   // TX slab col 200+j
                        bout2[(size_t)j * 4096 + i] = b;       // tx1T
                    }
                } else if (mode == MODE_TX2) {
                    if (j < 200) {
                        float xv = xf32[(size_t)i * 200 + j];
                        bout[(size_t)i * 608 + 400 + j] = f2bf(2.0f * v - xv);
                    }
                } else { // MODE_SALL
                    fout[(size_t)i * 640 + j] = v + vecj[j];
                }
            }
        }
    }
}

// ---------------------------------------------------------------------------
// prep kernels (f32 inputs -> bf16 staging)
// ---------------------------------------------------------------------------
__global__ void prep_x(const float* __restrict__ x, unsigned short* __restrict__ xA,
                       unsigned short* __restrict__ TX) {
    const int i = blockIdx.x;
    const int t = threadIdx.x;
    if (t < 224) {
        float v = (t < 200) ? x[(size_t)i * 200 + t] : 0.f;
        unsigned short b = f2bf(v);
        xA[(size_t)i * 224 + t] = b;
        if (t < 200) TX[(size_t)i * 608 + t] = b;
    }
    if (t >= 224 && t < 232) TX[(size_t)i * 608 + 600 + (t - 224)] = 0;
}

// out[c][r] = in[r][c] (f32 -> bf16), zero pad to [outRows][ldo]
__global__ void transpose_to_bf16(const float* __restrict__ in, int R, int C,
                                  unsigned short* __restrict__ out, int outRows, int ldo) {
    __shared__ float tile[32][33];
    const int c0 = blockIdx.x * 32;
    const int r0 = blockIdx.y * 32;
    const int tx = threadIdx.x, ty = threadIdx.y;  // 32 x 8
    for (int s = 0; s < 32; s += 8) {
        int r = r0 + ty + s, c = c0 + tx;
        tile[ty + s][tx] = (r < R && c < C) ? in[(size_t)r * C + c] : 0.f;
    }
    __syncthreads();
    for (int s = 0; s < 32; s += 8) {
        int orow = c0 + ty + s;
        int ocol = r0 + tx;
        if (orow < outRows && ocol < ldo)
            out[(size_t)orow * ldo + ocol] = f2bf(tile[tx][ty + s]);
    }
}

__global__ void prep_misc(const float* __restrict__ w1, const float* __restrict__ b1,
                          const float* __restrict__ w2, const float* __restrict__ b2,
                          const float* __restrict__ w3, const float* __restrict__ b3,
                          unsigned short* __restrict__ WallT, float* __restrict__ bias_all,
                          float* __restrict__ colsum, float* __restrict__ colsq,
                          unsigned short* __restrict__ tx1T) {
    const int tid0 = blockIdx.x * 256 + threadIdx.x;
    const int stride = gridDim.x * 256;
    // WallT[n][k] = Wall[k][n]; flat k index valid across orders.
    for (int p = tid0; p < 640 * 608; p += stride) {
        int n = p / 608, k = p % 608;
        float v = 0.f;
        if (n < 200)      { if (k < 200) v = w1[k * 200 + n]; }
        else if (n < 400) { if (k < 400) v = w2[k * 200 + (n - 200)]; }
        else if (n < 600) { if (k < 600) v = w3[k * 200 + (n - 400)]; }
        WallT[p] = f2bf(v);
    }
    for (int p = tid0; p < 640; p += stride) {
        float v = 0.f;
        if (p < 200) v = b1[p];
        else if (p < 400) v = b2[p - 200];
        else if (p < 600) v = b3[p - 400];
        bias_all[p] = v;
        colsum[p] = 0.f;
        colsq[p] = 0.f;
    }
    for (int p = tid0; p < 56 * 4096; p += stride)
        tx1T[200 * 4096 + p] = 0;   // zero pad rows 200..255
}

// ---------------------------------------------------------------------------
// row reductions
// ---------------------------------------------------------------------------
__global__ void rownorm(const unsigned short* __restrict__ attr, float* __restrict__ rninv) {
    const int i = blockIdx.x, t = threadIdx.x;
    const uint4* p = reinterpret_cast<const uint4*>(attr + (size_t)i * 4096);
    float s = 0.f;
#pragma unroll
    for (int c = 0; c < 2; c++) {
        uint4 u = p[t + c * 256];
        unsigned int uu[4] = {u.x, u.y, u.z, u.w};
#pragma unroll
        for (int e = 0; e < 4; e++) {
            float lo = __builtin_bit_cast(float, uu[e] << 16);
            float hi = __builtin_bit_cast(float, uu[e] & 0xffff0000u);
            s += lo * lo + hi * hi;
        }
    }
    __shared__ float red[4];
    for (int off = 32; off > 0; off >>= 1) s += __shfl_down(s, off, 64);
    if ((t & 63) == 0) red[t >> 6] = s;
    __syncthreads();
    if (t == 0) {
        float tot = red[0] + red[1] + red[2] + red[3];
        rninv[i] = 1.0f / fmaxf(sqrtf(tot), 1e-8f);
    }
}

__global__ void rowstats(const float* __restrict__ adj, float* __restrict__ rmaxinv,
                         float* __restrict__ dinv) {
    const int i = blockIdx.x, t = threadIdx.x;
    const float4* p = reinterpret_cast<const float4*>(adj + (size_t)i * 4096);
    float sm = 0.f, mx = -3.4e38f;
#pragma unroll
    for (int c = 0; c < 4; c++) {
        float4 v = p[t + c * 256];
        sm += (v.x + v.y) + (v.z + v.w);
        mx = fmaxf(mx, fmaxf(fmaxf(v.x, v.y), fmaxf(v.z, v.w)));
    }
    __shared__ float rs[4], rm[4];
    for (int off = 32; off > 0; off >>= 1) {
        sm += __shfl_down(sm, off, 64);
        mx = fmaxf(mx, __shfl_down(mx, off, 64));
    }
    if ((t & 63) == 0) { rs[t >> 6] = sm; rm[t >> 6] = mx; }
    __syncthreads();
    if (t == 0) {
        float S = rs[0] + rs[1] + rs[2] + rs[3];
        float M = fmaxf(fmaxf(rm[0], rm[1]), fmaxf(rm[2], rm[3]));
        float diag = adj[(size_t)i * 4096 + i];
        float deg = (S - diag) / M;
        rmaxinv[i] = 1.0f / M;
        dinv[i] = (deg > 0.f) ? rsqrtf(deg) : 0.f;
    }
}

// A_norm (f32, IN PLACE over adj: same-thread RMW) + W[p][q] = -dinv_p*dinv_q*A0[q][p]
__global__ void anorm_w(const float* __restrict__ adj, const float* __restrict__ rmaxinv,
                        const float* __restrict__ dinv,
                        float* __restrict__ outA, unsigned short* __restrict__ W) {
    __shared__ float wt[64][65];
    const int j0 = blockIdx.x * 64, i0 = blockIdx.y * 64;
    const int tx = threadIdx.x & 63, ty = threadIdx.x >> 6;
    const int j = j0 + tx;
    const float dj = dinv[j];
#pragma unroll
    for (int s = 0; s < 64; s += 4) {
        int i = i0 + s + ty;
        float a = adj[(size_t)i * 4096 + j] * rmaxinv[i];
        outA[(size_t)i * 4096 + j] = a;
        wt[s + ty][tx] = (i == j) ? 0.f : (-dinv[i] * dj * a);
    }
    __syncthreads();
    const int icol = i0 + tx;
#pragma unroll
    for (int s = 0; s < 64; s += 4) {
        int jrow = j0 + s + ty;
        W[(size_t)jrow * 4096 + icol] = f2bf(wt[tx][s + ty]);
    }
}

// ---------------------------------------------------------------------------
// BatchNorm: two-phase column stats over 4096 rows, 600 cols
// ---------------------------------------------------------------------------
__global__ void bn_partial(const float* __restrict__ sall, float* __restrict__ colsum,
                           float* __restrict__ colsq) {
    const int tx = threadIdx.x & 63, ty = threadIdx.x >> 6;
    const int c = blockIdx.x * 64 + tx;
    const int r0 = blockIdx.y * 256;
    float sm = 0.f, sq = 0.f;
    if (c < 600) {
        for (int s = 0; s < 256; s += 4) {
            float v = sall[(size_t)(r0 + s + ty) * 640 + c];
            sm += v; sq += v * v;
        }
    }
    __shared__ float ls[4][64], lq[4][64];
    ls[ty][tx] = sm; lq[ty][tx] = sq;
    __syncthreads();
    if (ty == 0 && c < 600) {
        atomicAdd(&colsum[c], ls[0][tx] + ls[1][tx] + ls[2][tx] + ls[3][tx]);
        atomicAdd(&colsq[c], lq[0][tx] + lq[1][tx] + lq[2][tx] + lq[3][tx]);
    }
}

__global__ void bn_write(const float* __restrict__ sall, const float* __restrict__ colsum,
                         const float* __restrict__ colsq, const float* __restrict__ gamma,
                         const float* __restrict__ beta, float* __restrict__ out) {
    const int tx = threadIdx.x & 63, ty = threadIdx.x >> 6;
    const int c = blockIdx.x * 64 + tx;
    if (c >= 600) return;
    const float mu  = colsum[c] * (1.f / 4096.f);
    float var = colsq[c] * (1.f / 4096.f) - mu * mu;
    var = fmaxf(var, 0.f);
    const float inv = rsqrtf(var + 1e-5f);
    const int cc = c % 200;
    const float g = gamma[cc] * inv, be = beta[cc];
    const size_t base = (size_t)(c / 200) * 819200;
    const int r0 = blockIdx.y * 256;
    for (int s = 0; s < 256; s += 4) {
        int r = r0 + s + ty;
        float v = sall[(size_t)r * 640 + c];
        out[base + (size_t)r * 200 + cc] = g * (v - mu) + be;
    }
}

// ---------------------------------------------------------------------------
extern "C" void kernel_launch(void* const* d_in, const int* in_sizes, int n_in,
                              void* d_out, int out_size, void* d_ws, size_t ws_size,
                              hipStream_t stream) {
    const float* x     = (const float*)d_in[0];
    const float* gglw  = (const float*)d_in[1];
    const float* gglb  = (const float*)d_in[2];
    const float* w1    = (const float*)d_in[3];
    const float* b1    = (const float*)d_in[4];
    const float* w2    = (const float*)d_in[5];
    const float* b2    = (const float*)d_in[6];
    const float* w3    = (const float*)d_in[7];
    const float* b3    = (const float*)d_in[8];
    const float* gamma = (const float*)d_in[9];
    const float* beta  = (const float*)d_in[10];
    float* out = (float*)d_out;

    char* ws = (char*)d_ws;
    size_t off = 0;
    auto alloc = [&](size_t bytes) -> void* {
        void* p = ws + off;
        off += (bytes + 255) & ~(size_t)255;
        return p;
    };
    unsigned short* TX    = (unsigned short*)alloc(4096ull * 608 * 2);
    unsigned short* WallT = (unsigned short*)alloc(640ull * 608 * 2);
    float*          sall  = (float*)alloc(4096ull * 640 * 4);
    float* bias_all = (float*)alloc(640 * 4);
    float* colsum   = (float*)alloc(640 * 4);
    float* colsq    = (float*)alloc(640 * 4);
    unsigned short* xA    = (unsigned short*)alloc(4096ull * 224 * 2);
    unsigned short* gglwT = (unsigned short*)alloc(4096ull * 224 * 2);
    unsigned short* xT    = (unsigned short*)alloc(256ull * 4096 * 2);
    unsigned short* tx1T  = (unsigned short*)alloc(256ull * 4096 * 2);
    float* rninv    = (float*)alloc(4096 * 4);
    float* rmaxinv  = (float*)alloc(4096 * 4);
    float* dinv     = (float*)alloc(4096 * 4);
    unsigned short* attrW = (unsigned short*)alloc(4096ull * 4096 * 2);  // attr, then W
    unsigned short* attr  = attrW;
    unsigned short* W     = attrW;
    float* adjf = out + 2457600;   // d_out A_norm slot (f32, 4096x4096) as adj scratch
    // total ws ~= 57 MB

    prep_misc<<<1024, 256, 0, stream>>>(w1, b1, w2, b2, w3, b3,
                                        WallT, bias_all, colsum, colsq, tx1T);
    prep_x<<<4096, 256, 0, stream>>>(x, xA, TX);
    transpose_to_bf16<<<dim3(8, 128), dim3(32, 8), 0, stream>>>(x, 4096, 200, xT, 256, 4096);
    transpose_to_bf16<<<dim3(128, 7), dim3(32, 8), 0, stream>>>(gglw, 200, 4096, gglwT, 4096, 224);

    // attr = sigmoid(x @ ggl_w + b)   [4096 x 4096] bf16 (internal)
    gemm_bt<<<dim3(32, 32), 256, 0, stream>>>(xA, gglwT, 224, 224, 224, MODE_ATTR,
                                              nullptr, attr, nullptr, nullptr, gglb, nullptr);
    rownorm<<<4096, 256, 0, stream>>>(attr, rninv);
    // adj = (attr @ attr^T) * rninv_i * rninv_j  -> f32 into d_out A_norm slot
    gemm_bt<<<dim3(32, 32), 256, 0, stream>>>(attr, attr, 4096, 4096, 4096, MODE_ADJ,
                                              adjf, nullptr, nullptr, rninv, rninv, nullptr);
    rowstats<<<4096, 256, 0, stream>>>(adjf, rmaxinv, dinv);
    // A_norm f32 in place; W bf16 into the (dead) attr slab
    anorm_w<<<dim3(64, 64), 256, 0, stream>>>(adjf, rmaxinv, dinv, adjf, W);
    // tx1 = M @ x
    gemm_bt<<<dim3(2, 32), 256, 0, stream>>>(W, xT, 4096, 4096, 4096, MODE_TX1,
                                             nullptr, TX, tx1T, nullptr, nullptr, nullptr);
    // tx2 = 2*(M @ tx1) - x
    gemm_bt<<<dim3(2, 32), 256, 0, stream>>>(W, tx1T, 4096, 4096, 4096, MODE_TX2,
                                             nullptr, TX, nullptr, nullptr, nullptr, x);
    // s_all = [tx0|tx1|tx2] @ Wall + bias_all  (f32)
    gemm_bt<<<dim3(5, 32), 256, 0, stream>>>(TX, WallT, 608, 608, 608, MODE_SALL,
                                             sall, nullptr, nullptr, nullptr, bias_all, nullptr);
    bn_partial<<<dim3(10, 16), 256, 0, stream>>>(sall, colsum, colsq);
    bn_write<<<dim3(10, 16), 256, 0, stream>>>(sall, colsum, colsq, gamma, beta, out);
}

// Round 9
// 464.051 us; speedup vs baseline: 2.7190x; 2.7190x over previous
//
#include <hip/hip_runtime.h>
#include <stdint.h>

// MGCN pipeline, R9 (R8 passed: 1261 us, absmax 0.031).
// Changes vs R8 (counters: adj GEMM 625us @ MfmaUtil 9% = latency-bound
// staging; tx GEMMs 64-block starved):
//  1. global_load_lds width=16 staging (m93->m97 ladder rung).
//  2. Split-K=8 tx1/tx2 GEMMs, f32 atomicAdd partials into d_out scratch
//     (x1..x3 region is dead until bn_write), + convert kernels.
// Predicted: adj ~220us @ MfmaUtil ~30%; total ~500-600us.

typedef __attribute__((ext_vector_type(8))) short short8;
typedef __attribute__((ext_vector_type(4))) float floatx4;

__device__ __forceinline__ unsigned short f2bf(float f) {
    unsigned int x = __builtin_bit_cast(unsigned int, f);
    x += 0x7fffu + ((x >> 16) & 1u);   // RNE
    return (unsigned short)(x >> 16);
}

#define MODE_ATTR 0
#define MODE_ADJ  1
#define MODE_TXP  2   // split-K partial: atomicAdd into f32 [4096][256]
#define MODE_SALL 4

// ---------------------------------------------------------------------------
// Generic bt-GEMM: C[i][j] = sum_k A[i][k]*Bt[j][k], bf16 in, f32 accum.
// Block 256 thr = 4 waves in 2x2, each wave 64x64 (4x4 mfma tiles).
// Staging: global_load_lds w=16; LDS dst = wave-uniform base + lane*16.
// ---------------------------------------------------------------------------
__global__ __launch_bounds__(256, 2)
void gemm_bt(const unsigned short* __restrict__ A, const unsigned short* __restrict__ Bt,
             int lda, int ldb, int kchunk, int mode,
             float* __restrict__ fout, unsigned short* __restrict__ bout,
             const float* __restrict__ veci, const float* __restrict__ vecj)
{
    __shared__ __attribute__((aligned(16))) unsigned short As[128 * 32];
    __shared__ __attribute__((aligned(16))) unsigned short Bs[128 * 32];
    const int t   = threadIdx.x;
    const int w   = t >> 6;
    const int m0  = blockIdx.y * 128;
    const int n0  = blockIdx.x * 128;
    const int q   = (t & 63) >> 4;
    const int m16 = t & 15;
    const int wm  = (w & 1) * 64;
    const int wn  = (w >> 1) * 64;
    const int kbeg = blockIdx.z * kchunk;
    const int kend = kbeg + kchunk;

    floatx4 acc[4][4];
#pragma unroll
    for (int a = 0; a < 4; a++)
#pragma unroll
        for (int b = 0; b < 4; b++)
            acc[a][b] = (floatx4){0.f, 0.f, 0.f, 0.f};

    for (int k0 = kbeg; k0 < kend; k0 += 32) {
        __syncthreads();   // prev iteration's LDS reads complete
#pragma unroll
        for (int c = 0; c < 2; c++) {
            const int off    = (c * 256 + t) * 16;   // byte offset in 8KB tile
            const int row    = off >> 6;             // 64 B per tile row
            const int colb   = off & 63;
            const int ldsoff = c * 4096 + w * 1024;  // wave-uniform base
            const unsigned short* ga = A + (size_t)(m0 + row) * lda + k0 + (colb >> 1);
            __builtin_amdgcn_global_load_lds(
                (const __attribute__((address_space(1))) unsigned int*)ga,
                (__attribute__((address_space(3))) unsigned int*)((char*)As + ldsoff),
                16, 0, 0);
            const unsigned short* gb = Bt + (size_t)(n0 + row) * ldb + k0 + (colb >> 1);
            __builtin_amdgcn_global_load_lds(
                (const __attribute__((address_space(1))) unsigned int*)gb,
                (__attribute__((address_space(3))) unsigned int*)((char*)Bs + ldsoff),
                16, 0, 0);
        }
        __syncthreads();   // compiler drains vmcnt before barrier -> LDS valid

        short8 af[4], bf[4];
#pragma unroll
        for (int mt = 0; mt < 4; mt++)
            af[mt] = *reinterpret_cast<const short8*>(&As[(wm + mt * 16 + m16) * 32 + q * 8]);
#pragma unroll
        for (int nt = 0; nt < 4; nt++)
            bf[nt] = *reinterpret_cast<const short8*>(&Bs[(wn + nt * 16 + m16) * 32 + q * 8]);
#pragma unroll
        for (int mt = 0; mt < 4; mt++)
#pragma unroll
            for (int nt = 0; nt < 4; nt++)
                acc[mt][nt] = __builtin_amdgcn_mfma_f32_16x16x32_bf16(af[mt], bf[nt], acc[mt][nt], 0, 0, 0);
    }

    // epilogue: C/D layout col = lane&15, row = q*4 + reg
#pragma unroll
    for (int mt = 0; mt < 4; mt++) {
#pragma unroll
        for (int nt = 0; nt < 4; nt++) {
#pragma unroll
            for (int r = 0; r < 4; r++) {
                const int i = m0 + wm + mt * 16 + q * 4 + r;
                const int j = n0 + wn + nt * 16 + m16;
                float v = acc[mt][nt][r];
                if (mode == MODE_ATTR) {
                    v += vecj[j];
                    v = 1.0f / (1.0f + __expf(-v));
                    bout[(size_t)i * 4096 + j] = f2bf(v);
                } else if (mode == MODE_ADJ) {
                    fout[(size_t)i * 4096 + j] = v * veci[i] * vecj[j];
                } else if (mode == MODE_TXP) {
                    atomicAdd(&fout[(size_t)i * 256 + j], v);
                } else { // MODE_SALL
                    fout[(size_t)i * 640 + j] = v + vecj[j];
                }
            }
        }
    }
}

// ---------------------------------------------------------------------------
// prep kernels (f32 inputs -> bf16 staging)
// ---------------------------------------------------------------------------
__global__ void prep_x(const float* __restrict__ x, unsigned short* __restrict__ xA,
                       unsigned short* __restrict__ TX) {
    const int i = blockIdx.x;
    const int t = threadIdx.x;
    if (t < 224) {
        float v = (t < 200) ? x[(size_t)i * 200 + t] : 0.f;
        unsigned short b = f2bf(v);
        xA[(size_t)i * 224 + t] = b;
        if (t < 200) TX[(size_t)i * 608 + t] = b;
    }
    if (t >= 224 && t < 232) TX[(size_t)i * 608 + 600 + (t - 224)] = 0;
}

// out[c][r] = in[r][c] (f32 -> bf16), zero pad to [outRows][ldo]
__global__ void transpose_to_bf16(const float* __restrict__ in, int R, int C,
                                  unsigned short* __restrict__ out, int outRows, int ldo) {
    __shared__ float tile[32][33];
    const int c0 = blockIdx.x * 32;
    const int r0 = blockIdx.y * 32;
    const int tx = threadIdx.x, ty = threadIdx.y;  // 32 x 8
    for (int s = 0; s < 32; s += 8) {
        int r = r0 + ty + s, c = c0 + tx;
        tile[ty + s][tx] = (r < R && c < C) ? in[(size_t)r * C + c] : 0.f;
    }
    __syncthreads();
    for (int s = 0; s < 32; s += 8) {
        int orow = c0 + ty + s;
        int ocol = r0 + tx;
        if (orow < outRows && ocol < ldo)
            out[(size_t)orow * ldo + ocol] = f2bf(tile[tx][ty + s]);
    }
}

__global__ void prep_misc(const float* __restrict__ w1, const float* __restrict__ b1,
                          const float* __restrict__ w2, const float* __restrict__ b2,
                          const float* __restrict__ w3, const float* __restrict__ b3,
                          unsigned short* __restrict__ WallT, float* __restrict__ bias_all,
                          float* __restrict__ colsum, float* __restrict__ colsq,
                          float* __restrict__ txf) {
    const int tid0 = blockIdx.x * 256 + threadIdx.x;
    const int stride = gridDim.x * 256;
    // WallT[n][k] = Wall[k][n]; flat k index valid across orders.
    for (int p = tid0; p < 640 * 608; p += stride) {
        int n = p / 608, k = p % 608;
        float v = 0.f;
        if (n < 200)      { if (k < 200) v = w1[k * 200 + n]; }
        else if (n < 400) { if (k < 400) v = w2[k * 200 + (n - 200)]; }
        else if (n < 600) { if (k < 600) v = w3[k * 200 + (n - 400)]; }
        WallT[p] = f2bf(v);
    }
    for (int p = tid0; p < 640; p += stride) {
        float v = 0.f;
        if (p < 200) v = b1[p];
        else if (p < 400) v = b2[p - 200];
        else if (p < 600) v = b3[p - 400];
        bias_all[p] = v;
        colsum[p] = 0.f;
        colsq[p] = 0.f;
    }
    // zero split-K accumulators (tx1f + tx2f contiguous, 2M floats)
    for (int p = tid0; p < 2 * 1048576; p += stride)
        txf[p] = 0.f;
}

// ---------------------------------------------------------------------------
// row reductions
// ---------------------------------------------------------------------------
__global__ void rownorm(const unsigned short* __restrict__ attr, float* __restrict__ rninv) {
    const int i = blockIdx.x, t = threadIdx.x;
    const uint4* p = reinterpret_cast<const uint4*>(attr + (size_t)i * 4096);
    float s = 0.f;
#pragma unroll
    for (int c = 0; c < 2; c++) {
        uint4 u = p[t + c * 256];
        unsigned int uu[4] = {u.x, u.y, u.z, u.w};
#pragma unroll
        for (int e = 0; e < 4; e++) {
            float lo = __builtin_bit_cast(float, uu[e] << 16);
            float hi = __builtin_bit_cast(float, uu[e] & 0xffff0000u);
            s += lo * lo + hi * hi;
        }
    }
    __shared__ float red[4];
    for (int off = 32; off > 0; off >>= 1) s += __shfl_down(s, off, 64);
    if ((t & 63) == 0) red[t >> 6] = s;
    __syncthreads();
    if (t == 0) {
        float tot = red[0] + red[1] + red[2] + red[3];
        rninv[i] = 1.0f / fmaxf(sqrtf(tot), 1e-8f);
    }
}

__global__ void rowstats(const float* __restrict__ adj, float* __restrict__ rmaxinv,
                         float* __restrict__ dinv) {
    const int i = blockIdx.x, t = threadIdx.x;
    const float4* p = reinterpret_cast<const float4*>(adj + (size_t)i * 4096);
    float sm = 0.f, mx = -3.4e38f;
#pragma unroll
    for (int c = 0; c < 4; c++) {
        float4 v = p[t + c * 256];
        sm += (v.x + v.y) + (v.z + v.w);
        mx = fmaxf(mx, fmaxf(fmaxf(v.x, v.y), fmaxf(v.z, v.w)));
    }
    __shared__ float rs[4], rm[4];
    for (int off = 32; off > 0; off >>= 1) {
        sm += __shfl_down(sm, off, 64);
        mx = fmaxf(mx, __shfl_down(mx, off, 64));
    }
    if ((t & 63) == 0) { rs[t >> 6] = sm; rm[t >> 6] = mx; }
    __syncthreads();
    if (t == 0) {
        float S = rs[0] + rs[1] + rs[2] + rs[3];
        float M = fmaxf(fmaxf(rm[0], rm[1]), fmaxf(rm[2], rm[3]));
        float diag = adj[(size_t)i * 4096 + i];
        float deg = (S - diag) / M;
        rmaxinv[i] = 1.0f / M;
        dinv[i] = (deg > 0.f) ? rsqrtf(deg) : 0.f;
    }
}

// A_norm (f32, IN PLACE over adj: same-thread RMW) + W[p][q] = -dinv_p*dinv_q*A0[q][p]
__global__ void anorm_w(const float* __restrict__ adj, const float* __restrict__ rmaxinv,
                        const float* __restrict__ dinv,
                        float* __restrict__ outA, unsigned short* __restrict__ W) {
    __shared__ float wt[64][65];
    const int j0 = blockIdx.x * 64, i0 = blockIdx.y * 64;
    const int tx = threadIdx.x & 63, ty = threadIdx.x >> 6;
    const int j = j0 + tx;
    const float dj = dinv[j];
#pragma unroll
    for (int s = 0; s < 64; s += 4) {
        int i = i0 + s + ty;
        float a = adj[(size_t)i * 4096 + j] * rmaxinv[i];
        outA[(size_t)i * 4096 + j] = a;
        wt[s + ty][tx] = (i == j) ? 0.f : (-dinv[i] * dj * a);
    }
    __syncthreads();
    const int icol = i0 + tx;
#pragma unroll
    for (int s = 0; s < 64; s += 4) {
        int jrow = j0 + s + ty;
        W[(size_t)jrow * 4096 + icol] = f2bf(wt[tx][s + ty]);
    }
}

// ---------------------------------------------------------------------------
// split-K converts
// ---------------------------------------------------------------------------
// tx1f [4096][256] -> TX slab col 200+j (j<200) + tx1T[j][i] bf16 (all j<256)
__global__ void tx_convert1(const float* __restrict__ tf, unsigned short* __restrict__ TX,
                            unsigned short* __restrict__ tx1T) {
    __shared__ float tile[32][33];
    const int j0 = blockIdx.x * 32;
    const int i0 = blockIdx.y * 32;
    const int tx = threadIdx.x, ty = threadIdx.y;  // 32 x 8
    for (int s = 0; s < 32; s += 8) {
        int i = i0 + ty + s, j = j0 + tx;
        float v = tf[(size_t)i * 256 + j];
        tile[ty + s][tx] = v;
        if (j < 200) TX[(size_t)i * 608 + 200 + j] = f2bf(v);
    }
    __syncthreads();
    for (int s = 0; s < 32; s += 8) {
        int jr = j0 + ty + s;
        int ic = i0 + tx;
        tx1T[(size_t)jr * 4096 + ic] = f2bf(tile[tx][ty + s]);
    }
}

// TX col 400+j = 2*tx2f - x
__global__ void tx_convert2(const float* __restrict__ tf, const float* __restrict__ x,
                            unsigned short* __restrict__ TX) {
    int idx = blockIdx.x * 256 + threadIdx.x;
    if (idx >= 4096 * 200) return;
    int i = idx / 200, j = idx % 200;
    TX[(size_t)i * 608 + 400 + j] = f2bf(2.f * tf[(size_t)i * 256 + j] - x[idx]);
}

// ---------------------------------------------------------------------------
// BatchNorm: two-phase column stats over 4096 rows, 600 cols
// ---------------------------------------------------------------------------
__global__ void bn_partial(const float* __restrict__ sall, float* __restrict__ colsum,
                           float* __restrict__ colsq) {
    const int tx = threadIdx.x & 63, ty = threadIdx.x >> 6;
    const int c = blockIdx.x * 64 + tx;
    const int r0 = blockIdx.y * 256;
    float sm = 0.f, sq = 0.f;
    if (c < 600) {
        for (int s = 0; s < 256; s += 4) {
            float v = sall[(size_t)(r0 + s + ty) * 640 + c];
            sm += v; sq += v * v;
        }
    }
    __shared__ float ls[4][64], lq[4][64];
    ls[ty][tx] = sm; lq[ty][tx] = sq;
    __syncthreads();
    if (ty == 0 && c < 600) {
        atomicAdd(&colsum[c], ls[0][tx] + ls[1][tx] + ls[2][tx] + ls[3][tx]);
        atomicAdd(&colsq[c], lq[0][tx] + lq[1][tx] + lq[2][tx] + lq[3][tx]);
    }
}

__global__ void bn_write(const float* __restrict__ sall, const float* __restrict__ colsum,
                         const float* __restrict__ colsq, const float* __restrict__ gamma,
                         const float* __restrict__ beta, float* __restrict__ out) {
    const int tx = threadIdx.x & 63, ty = threadIdx.x >> 6;
    const int c = blockIdx.x * 64 + tx;
    if (c >= 600) return;
    const float mu  = colsum[c] * (1.f / 4096.f);
    float var = colsq[c] * (1.f / 4096.f) - mu * mu;
    var = fmaxf(var, 0.f);
    const float inv = rsqrtf(var + 1e-5f);
    const int cc = c % 200;
    const float g = gamma[cc] * inv, be = beta[cc];
    const size_t base = (size_t)(c / 200) * 819200;
    const int r0 = blockIdx.y * 256;
    for (int s = 0; s < 256; s += 4) {
        int r = r0 + s + ty;
        float v = sall[(size_t)r * 640 + c];
        out[base + (size_t)r * 200 + cc] = g * (v - mu) + be;
    }
}

// ---------------------------------------------------------------------------
extern "C" void kernel_launch(void* const* d_in, const int* in_sizes, int n_in,
                              void* d_out, int out_size, void* d_ws, size_t ws_size,
                              hipStream_t stream) {
    const float* x     = (const float*)d_in[0];
    const float* gglw  = (const float*)d_in[1];
    const float* gglb  = (const float*)d_in[2];
    const float* w1    = (const float*)d_in[3];
    const float* b1    = (const float*)d_in[4];
    const float* w2    = (const float*)d_in[5];
    const float* b2    = (const float*)d_in[6];
    const float* w3    = (const float*)d_in[7];
    const float* b3    = (const float*)d_in[8];
    const float* gamma = (const float*)d_in[9];
    const float* beta  = (const float*)d_in[10];
    float* out = (float*)d_out;

    char* ws = (char*)d_ws;
    size_t off = 0;
    auto alloc = [&](size_t bytes) -> void* {
        void* p = ws + off;
        off += (bytes + 255) & ~(size_t)255;
        return p;
    };
    unsigned short* TX    = (unsigned short*)alloc(4096ull * 608 * 2);
    unsigned short* WallT = (unsigned short*)alloc(640ull * 608 * 2);
    float*          sall  = (float*)alloc(4096ull * 640 * 4);
    float* bias_all = (float*)alloc(640 * 4);
    float* colsum   = (float*)alloc(640 * 4);
    float* colsq    = (float*)alloc(640 * 4);
    unsigned short* xA    = (unsigned short*)alloc(4096ull * 224 * 2);
    unsigned short* gglwT = (unsigned short*)alloc(4096ull * 224 * 2);
    unsigned short* xT    = (unsigned short*)alloc(256ull * 4096 * 2);
    unsigned short* tx1T  = (unsigned short*)alloc(256ull * 4096 * 2);
    float* rninv    = (float*)alloc(4096 * 4);
    float* rmaxinv  = (float*)alloc(4096 * 4);
    float* dinv     = (float*)alloc(4096 * 4);
    unsigned short* attrW = (unsigned short*)alloc(4096ull * 4096 * 2);  // attr, then W
    unsigned short* attr  = attrW;
    unsigned short* W     = attrW;
    // d_out scratch: x1..x3 region (2457600 f32) is dead until bn_write.
    float* tx1f = out;                 // [4096][256] f32 split-K accumulator
    float* tx2f = out + 1048576;       // [4096][256]
    float* adjf = out + 2457600;       // A_norm slot (f32 4096x4096) as adj

    prep_misc<<<1024, 256, 0, stream>>>(w1, b1, w2, b2, w3, b3,
                                        WallT, bias_all, colsum, colsq, tx1f);
    prep_x<<<4096, 256, 0, stream>>>(x, xA, TX);
    transpose_to_bf16<<<dim3(8, 128), dim3(32, 8), 0, stream>>>(x, 4096, 200, xT, 256, 4096);
    transpose_to_bf16<<<dim3(128, 7), dim3(32, 8), 0, stream>>>(gglw, 200, 4096, gglwT, 4096, 224);

    // attr = sigmoid(x @ ggl_w + b)
    gemm_bt<<<dim3(32, 32), 256, 0, stream>>>(xA, gglwT, 224, 224, 224, MODE_ATTR,
                                              nullptr, attr, nullptr, gglb);
    rownorm<<<4096, 256, 0, stream>>>(attr, rninv);
    // adj = (attr @ attr^T) * rninv_i * rninv_j  -> f32 into d_out A_norm slot
    gemm_bt<<<dim3(32, 32), 256, 0, stream>>>(attr, attr, 4096, 4096, 4096, MODE_ADJ,
                                              adjf, nullptr, rninv, rninv);
    rowstats<<<4096, 256, 0, stream>>>(adjf, rmaxinv, dinv);
    anorm_w<<<dim3(64, 64), 256, 0, stream>>>(adjf, rmaxinv, dinv, adjf, W);
    // tx1 = M @ x  (split-K=8, partials into tx1f)
    gemm_bt<<<dim3(2, 32, 8), 256, 0, stream>>>(W, xT, 4096, 4096, 512, MODE_TXP,
                                                tx1f, nullptr, nullptr, nullptr);
    tx_convert1<<<dim3(8, 128), dim3(32, 8), 0, stream>>>(tx1f, TX, tx1T);
    // tx2 = 2*(M @ tx1) - x  (split-K=8)
    gemm_bt<<<dim3(2, 32, 8), 256, 0, stream>>>(W, tx1T, 4096, 4096, 512, MODE_TXP,
                                                tx2f, nullptr, nullptr, nullptr);
    tx_convert2<<<3200, 256, 0, stream>>>(tx2f, x, TX);
    // s_all = [tx0|tx1|tx2] @ Wall + bias_all
    gemm_bt<<<dim3(5, 32), 256, 0, stream>>>(TX, WallT, 608, 608, 608, MODE_SALL,
                                             sall, nullptr, nullptr, bias_all);
    bn_partial<<<dim3(10, 16), 256, 0, stream>>>(sall, colsum, colsq);
    bn_write<<<dim3(10, 16), 256, 0, stream>>>(sall, colsum, colsq, gamma, beta, out);
}

// Round 10
// 461.550 us; speedup vs baseline: 2.7338x; 1.0054x over previous
//
#include <hip/hip_runtime.h>
#include <stdint.h>

// MGCN pipeline, R10 (R9: 464 us passed; adj GEMM 170us @ 809 TF = m97
// plateau, 35% MfmaUtil).
// Changes vs R9:
//  1. adj GEMM exploits symmetry: only n0>=m0 blocks compute (528/1024),
//     off-diagonal tiles mirror-write both [i][j] and [j][i].
//  2. tx1/tx2 split-K uses per-slice outputs (32MB ws slab, reused) instead
//     of 8-way-contended atomicAdd; slice-sum folded into convert kernels.
//     Falls back to R9 atomic path if ws_size < 92 MiB.
// Predicted: adj ~95us, total ~370-400us.

typedef __attribute__((ext_vector_type(8))) short short8;
typedef __attribute__((ext_vector_type(4))) float floatx4;

__device__ __forceinline__ unsigned short f2bf(float f) {
    unsigned int x = __builtin_bit_cast(unsigned int, f);
    x += 0x7fffu + ((x >> 16) & 1u);   // RNE
    return (unsigned short)(x >> 16);
}

#define MODE_ATTR 0
#define MODE_ADJ  1   // symmetric: computes upper triangle, mirrors writes
#define MODE_TXP  2   // split-K partial: atomicAdd into f32 [4096][256]
#define MODE_TXS  3   // split-K partial: private slice write (no atomics)
#define MODE_SALL 4

// ---------------------------------------------------------------------------
// Generic bt-GEMM: C[i][j] = sum_k A[i][k]*Bt[j][k], bf16 in, f32 accum.
// Block 256 thr = 4 waves in 2x2, each wave 64x64 (4x4 mfma tiles).
// Staging: global_load_lds w=16; LDS dst = wave-uniform base + lane*16.
// ---------------------------------------------------------------------------
__global__ __launch_bounds__(256, 2)
void gemm_bt(const unsigned short* __restrict__ A, const unsigned short* __restrict__ Bt,
             int lda, int ldb, int kchunk, int mode,
             float* __restrict__ fout, unsigned short* __restrict__ bout,
             const float* __restrict__ veci, const float* __restrict__ vecj)
{
    __shared__ __attribute__((aligned(16))) unsigned short As[128 * 32];
    __shared__ __attribute__((aligned(16))) unsigned short Bs[128 * 32];
    const int m0  = blockIdx.y * 128;
    const int n0  = blockIdx.x * 128;
    if (mode == MODE_ADJ && n0 < m0) return;   // symmetric: skip lower triangle
    const int t   = threadIdx.x;
    const int w   = t >> 6;
    const int q   = (t & 63) >> 4;
    const int m16 = t & 15;
    const int wm  = (w & 1) * 64;
    const int wn  = (w >> 1) * 64;
    const int kbeg = blockIdx.z * kchunk;
    const int kend = kbeg + kchunk;

    floatx4 acc[4][4];
#pragma unroll
    for (int a = 0; a < 4; a++)
#pragma unroll
        for (int b = 0; b < 4; b++)
            acc[a][b] = (floatx4){0.f, 0.f, 0.f, 0.f};

    for (int k0 = kbeg; k0 < kend; k0 += 32) {
        __syncthreads();   // prev iteration's LDS reads complete
#pragma unroll
        for (int c = 0; c < 2; c++) {
            const int off    = (c * 256 + t) * 16;   // byte offset in 8KB tile
            const int row    = off >> 6;             // 64 B per tile row
            const int colb   = off & 63;
            const int ldsoff = c * 4096 + w * 1024;  // wave-uniform base
            const unsigned short* ga = A + (size_t)(m0 + row) * lda + k0 + (colb >> 1);
            __builtin_amdgcn_global_load_lds(
                (const __attribute__((address_space(1))) unsigned int*)ga,
                (__attribute__((address_space(3))) unsigned int*)((char*)As + ldsoff),
                16, 0, 0);
            const unsigned short* gb = Bt + (size_t)(n0 + row) * ldb + k0 + (colb >> 1);
            __builtin_amdgcn_global_load_lds(
                (const __attribute__((address_space(1))) unsigned int*)gb,
                (__attribute__((address_space(3))) unsigned int*)((char*)Bs + ldsoff),
                16, 0, 0);
        }
        __syncthreads();   // compiler drains vmcnt before barrier -> LDS valid

        short8 af[4], bf[4];
#pragma unroll
        for (int mt = 0; mt < 4; mt++)
            af[mt] = *reinterpret_cast<const short8*>(&As[(wm + mt * 16 + m16) * 32 + q * 8]);
#pragma unroll
        for (int nt = 0; nt < 4; nt++)
            bf[nt] = *reinterpret_cast<const short8*>(&Bs[(wn + nt * 16 + m16) * 32 + q * 8]);
#pragma unroll
        for (int mt = 0; mt < 4; mt++)
#pragma unroll
            for (int nt = 0; nt < 4; nt++)
                acc[mt][nt] = __builtin_amdgcn_mfma_f32_16x16x32_bf16(af[mt], bf[nt], acc[mt][nt], 0, 0, 0);
    }

    // epilogue: C/D layout col = lane&15, row = q*4 + reg
#pragma unroll
    for (int mt = 0; mt < 4; mt++) {
#pragma unroll
        for (int nt = 0; nt < 4; nt++) {
#pragma unroll
            for (int r = 0; r < 4; r++) {
                const int i = m0 + wm + mt * 16 + q * 4 + r;
                const int j = n0 + wn + nt * 16 + m16;
                float v = acc[mt][nt][r];
                if (mode == MODE_ATTR) {
                    v += vecj[j];
                    v = 1.0f / (1.0f + __expf(-v));
                    bout[(size_t)i * 4096 + j] = f2bf(v);
                } else if (mode == MODE_ADJ) {
                    float a = v * veci[i] * vecj[j];
                    fout[(size_t)i * 4096 + j] = a;
                    if (n0 > m0) fout[(size_t)j * 4096 + i] = a;   // mirror
                } else if (mode == MODE_TXP) {
                    atomicAdd(&fout[(size_t)i * 256 + j], v);
                } else if (mode == MODE_TXS) {
                    fout[(size_t)blockIdx.z * 1048576 + (size_t)i * 256 + j] = v;
                } else { // MODE_SALL
                    fout[(size_t)i * 640 + j] = v + vecj[j];
                }
            }
        }
    }
}

// ---------------------------------------------------------------------------
// prep kernels (f32 inputs -> bf16 staging)
// ---------------------------------------------------------------------------
__global__ void prep_x(const float* __restrict__ x, unsigned short* __restrict__ xA,
                       unsigned short* __restrict__ TX) {
    const int i = blockIdx.x;
    const int t = threadIdx.x;
    if (t < 224) {
        float v = (t < 200) ? x[(size_t)i * 200 + t] : 0.f;
        unsigned short b = f2bf(v);
        xA[(size_t)i * 224 + t] = b;
        if (t < 200) TX[(size_t)i * 608 + t] = b;
    }
    if (t >= 224 && t < 232) TX[(size_t)i * 608 + 600 + (t - 224)] = 0;
}

// out[c][r] = in[r][c] (f32 -> bf16), zero pad to [outRows][ldo]
__global__ void transpose_to_bf16(const float* __restrict__ in, int R, int C,
                                  unsigned short* __restrict__ out, int outRows, int ldo) {
    __shared__ float tile[32][33];
    const int c0 = blockIdx.x * 32;
    const int r0 = blockIdx.y * 32;
    const int tx = threadIdx.x, ty = threadIdx.y;  // 32 x 8
    for (int s = 0; s < 32; s += 8) {
        int r = r0 + ty + s, c = c0 + tx;
        tile[ty + s][tx] = (r < R && c < C) ? in[(size_t)r * C + c] : 0.f;
    }
    __syncthreads();
    for (int s = 0; s < 32; s += 8) {
        int orow = c0 + ty + s;
        int ocol = r0 + tx;
        if (orow < outRows && ocol < ldo)
            out[(size_t)orow * ldo + ocol] = f2bf(tile[tx][ty + s]);
    }
}

__global__ void prep_misc(const float* __restrict__ w1, const float* __restrict__ b1,
                          const float* __restrict__ w2, const float* __restrict__ b2,
                          const float* __restrict__ w3, const float* __restrict__ b3,
                          unsigned short* __restrict__ WallT, float* __restrict__ bias_all,
                          float* __restrict__ colsum, float* __restrict__ colsq,
                          float* __restrict__ txf) {
    const int tid0 = blockIdx.x * 256 + threadIdx.x;
    const int stride = gridDim.x * 256;
    // WallT[n][k] = Wall[k][n]; flat k index valid across orders.
    for (int p = tid0; p < 640 * 608; p += stride) {
        int n = p / 608, k = p % 608;
        float v = 0.f;
        if (n < 200)      { if (k < 200) v = w1[k * 200 + n]; }
        else if (n < 400) { if (k < 400) v = w2[k * 200 + (n - 200)]; }
        else if (n < 600) { if (k < 600) v = w3[k * 200 + (n - 400)]; }
        WallT[p] = f2bf(v);
    }
    for (int p = tid0; p < 640; p += stride) {
        float v = 0.f;
        if (p < 200) v = b1[p];
        else if (p < 400) v = b2[p - 200];
        else if (p < 600) v = b3[p - 400];
        bias_all[p] = v;
        colsum[p] = 0.f;
        colsq[p] = 0.f;
    }
    // zero split-K atomic accumulators (fallback path; cheap, always done)
    for (int p = tid0; p < 2 * 1048576; p += stride)
        txf[p] = 0.f;
}

// ---------------------------------------------------------------------------
// row reductions
// ---------------------------------------------------------------------------
__global__ void rownorm(const unsigned short* __restrict__ attr, float* __restrict__ rninv) {
    const int i = blockIdx.x, t = threadIdx.x;
    const uint4* p = reinterpret_cast<const uint4*>(attr + (size_t)i * 4096);
    float s = 0.f;
#pragma unroll
    for (int c = 0; c < 2; c++) {
        uint4 u = p[t + c * 256];
        unsigned int uu[4] = {u.x, u.y, u.z, u.w};
#pragma unroll
        for (int e = 0; e < 4; e++) {
            float lo = __builtin_bit_cast(float, uu[e] << 16);
            float hi = __builtin_bit_cast(float, uu[e] & 0xffff0000u);
            s += lo * lo + hi * hi;
        }
    }
    __shared__ float red[4];
    for (int off = 32; off > 0; off >>= 1) s += __shfl_down(s, off, 64);
    if ((t & 63) == 0) red[t >> 6] = s;
    __syncthreads();
    if (t == 0) {
        float tot = red[0] + red[1] + red[2] + red[3];
        rninv[i] = 1.0f / fmaxf(sqrtf(tot), 1e-8f);
    }
}

__global__ void rowstats(const float* __restrict__ adj, float* __restrict__ rmaxinv,
                         float* __restrict__ dinv) {
    const int i = blockIdx.x, t = threadIdx.x;
    const float4* p = reinterpret_cast<const float4*>(adj + (size_t)i * 4096);
    float sm = 0.f, mx = -3.4e38f;
#pragma unroll
    for (int c = 0; c < 4; c++) {
        float4 v = p[t + c * 256];
        sm += (v.x + v.y) + (v.z + v.w);
        mx = fmaxf(mx, fmaxf(fmaxf(v.x, v.y), fmaxf(v.z, v.w)));
    }
    __shared__ float rs[4], rm[4];
    for (int off = 32; off > 0; off >>= 1) {
        sm += __shfl_down(sm, off, 64);
        mx = fmaxf(mx, __shfl_down(mx, off, 64));
    }
    if ((t & 63) == 0) { rs[t >> 6] = sm; rm[t >> 6] = mx; }
    __syncthreads();
    if (t == 0) {
        float S = rs[0] + rs[1] + rs[2] + rs[3];
        float M = fmaxf(fmaxf(rm[0], rm[1]), fmaxf(rm[2], rm[3]));
        float diag = adj[(size_t)i * 4096 + i];
        float deg = (S - diag) / M;
        rmaxinv[i] = 1.0f / M;
        dinv[i] = (deg > 0.f) ? rsqrtf(deg) : 0.f;
    }
}

// A_norm (f32, IN PLACE over adj: same-thread RMW) + W[p][q] = -dinv_p*dinv_q*A0[q][p]
__global__ void anorm_w(const float* __restrict__ adj, const float* __restrict__ rmaxinv,
                        const float* __restrict__ dinv,
                        float* __restrict__ outA, unsigned short* __restrict__ W) {
    __shared__ float wt[64][65];
    const int j0 = blockIdx.x * 64, i0 = blockIdx.y * 64;
    const int tx = threadIdx.x & 63, ty = threadIdx.x >> 6;
    const int j = j0 + tx;
    const float dj = dinv[j];
#pragma unroll
    for (int s = 0; s < 64; s += 4) {
        int i = i0 + s + ty;
        float a = adj[(size_t)i * 4096 + j] * rmaxinv[i];
        outA[(size_t)i * 4096 + j] = a;
        wt[s + ty][tx] = (i == j) ? 0.f : (-dinv[i] * dj * a);
    }
    __syncthreads();
    const int icol = i0 + tx;
#pragma unroll
    for (int s = 0; s < 64; s += 4) {
        int jrow = j0 + s + ty;
        W[(size_t)jrow * 4096 + icol] = f2bf(wt[tx][s + ty]);
    }
}

// ---------------------------------------------------------------------------
// split-K converts (sum nslices slices of [4096][256])
// ---------------------------------------------------------------------------
__global__ void tx_convert1(const float* __restrict__ tf, int nslices,
                            unsigned short* __restrict__ TX,
                            unsigned short* __restrict__ tx1T) {
    __shared__ float tile[32][33];
    const int j0 = blockIdx.x * 32;
    const int i0 = blockIdx.y * 32;
    const int tx = threadIdx.x, ty = threadIdx.y;  // 32 x 8
    for (int s = 0; s < 32; s += 8) {
        int i = i0 + ty + s, j = j0 + tx;
        float v = 0.f;
        for (int z = 0; z < nslices; z++)
            v += tf[(size_t)z * 1048576 + (size_t)i * 256 + j];
        tile[ty + s][tx] = v;
        if (j < 200) TX[(size_t)i * 608 + 200 + j] = f2bf(v);
    }
    __syncthreads();
    for (int s = 0; s < 32; s += 8) {
        int jr = j0 + ty + s;
        int ic = i0 + tx;
        tx1T[(size_t)jr * 4096 + ic] = f2bf(tile[tx][ty + s]);
    }
}

// TX col 400+j = 2*sum_z tf - x
__global__ void tx_convert2(const float* __restrict__ tf, int nslices,
                            const float* __restrict__ x,
                            unsigned short* __restrict__ TX) {
    int idx = blockIdx.x * 256 + threadIdx.x;
    if (idx >= 4096 * 200) return;
    int i = idx / 200, j = idx % 200;
    float v = 0.f;
    for (int z = 0; z < nslices; z++)
        v += tf[(size_t)z * 1048576 + (size_t)i * 256 + j];
    TX[(size_t)i * 608 + 400 + j] = f2bf(2.f * v - x[idx]);
}

// ---------------------------------------------------------------------------
// BatchNorm: two-phase column stats over 4096 rows, 600 cols
// ---------------------------------------------------------------------------
__global__ void bn_partial(const float* __restrict__ sall, float* __restrict__ colsum,
                           float* __restrict__ colsq) {
    const int tx = threadIdx.x & 63, ty = threadIdx.x >> 6;
    const int c = blockIdx.x * 64 + tx;
    const int r0 = blockIdx.y * 256;
    float sm = 0.f, sq = 0.f;
    if (c < 600) {
        for (int s = 0; s < 256; s += 4) {
            float v = sall[(size_t)(r0 + s + ty) * 640 + c];
            sm += v; sq += v * v;
        }
    }
    __shared__ float ls[4][64], lq[4][64];
    ls[ty][tx] = sm; lq[ty][tx] = sq;
    __syncthreads();
    if (ty == 0 && c < 600) {
        atomicAdd(&colsum[c], ls[0][tx] + ls[1][tx] + ls[2][tx] + ls[3][tx]);
        atomicAdd(&colsq[c], lq[0][tx] + lq[1][tx] + lq[2][tx] + lq[3][tx]);
    }
}

__global__ void bn_write(const float* __restrict__ sall, const float* __restrict__ colsum,
                         const float* __restrict__ colsq, const float* __restrict__ gamma,
                         const float* __restrict__ beta, float* __restrict__ out) {
    const int tx = threadIdx.x & 63, ty = threadIdx.x >> 6;
    const int c = blockIdx.x * 64 + tx;
    if (c >= 600) return;
    const float mu  = colsum[c] * (1.f / 4096.f);
    float var = colsq[c] * (1.f / 4096.f) - mu * mu;
    var = fmaxf(var, 0.f);
    const float inv = rsqrtf(var + 1e-5f);
    const int cc = c % 200;
    const float g = gamma[cc] * inv, be = beta[cc];
    const size_t base = (size_t)(c / 200) * 819200;
    const int r0 = blockIdx.y * 256;
    for (int s = 0; s < 256; s += 4) {
        int r = r0 + s + ty;
        float v = sall[(size_t)r * 640 + c];
        out[base + (size_t)r * 200 + cc] = g * (v - mu) + be;
    }
}

// ---------------------------------------------------------------------------
extern "C" void kernel_launch(void* const* d_in, const int* in_sizes, int n_in,
                              void* d_out, int out_size, void* d_ws, size_t ws_size,
                              hipStream_t stream) {
    const float* x     = (const float*)d_in[0];
    const float* gglw  = (const float*)d_in[1];
    const float* gglb  = (const float*)d_in[2];
    const float* w1    = (const float*)d_in[3];
    const float* b1    = (const float*)d_in[4];
    const float* w2    = (const float*)d_in[5];
    const float* b2    = (const float*)d_in[6];
    const float* w3    = (const float*)d_in[7];
    const float* b3    = (const float*)d_in[8];
    const float* gamma = (const float*)d_in[9];
    const float* beta  = (const float*)d_in[10];
    float* out = (float*)d_out;

    char* ws = (char*)d_ws;
    size_t off = 0;
    auto alloc = [&](size_t bytes) -> void* {
        void* p = ws + off;
        off += (bytes + 255) & ~(size_t)255;
        return p;
    };
    unsigned short* TX    = (unsigned short*)alloc(4096ull * 608 * 2);
    unsigned short* WallT = (unsigned short*)alloc(640ull * 608 * 2);
    float*          sall  = (float*)alloc(4096ull * 640 * 4);
    float* bias_all = (float*)alloc(640 * 4);
    float* colsum   = (float*)alloc(640 * 4);
    float* colsq    = (float*)alloc(640 * 4);
    unsigned short* xA    = (unsigned short*)alloc(4096ull * 224 * 2);
    unsigned short* gglwT = (unsigned short*)alloc(4096ull * 224 * 2);
    unsigned short* xT    = (unsigned short*)alloc(256ull * 4096 * 2);
    unsigned short* tx1T  = (unsigned short*)alloc(256ull * 4096 * 2);
    float* rninv    = (float*)alloc(4096 * 4);
    float* rmaxinv  = (float*)alloc(4096 * 4);
    float* dinv     = (float*)alloc(4096 * 4);
    unsigned short* attrW = (unsigned short*)alloc(4096ull * 4096 * 2);  // attr, then W
    unsigned short* attr  = attrW;
    unsigned short* W     = attrW;
    float* txs = (float*)alloc(8ull * 1048576 * 4);   // 32MB split-K slices (if ws allows)
    const bool slicepath = (off <= ws_size);          // ~90MB needed for slice path
    // d_out scratch: x1..x3 region (2457600 f32) dead until bn_write.
    float* tx1f = out;                 // atomic-path accumulators
    float* tx2f = out + 1048576;
    float* adjf = out + 2457600;       // A_norm slot (f32 4096x4096) as adj

    prep_misc<<<1024, 256, 0, stream>>>(w1, b1, w2, b2, w3, b3,
                                        WallT, bias_all, colsum, colsq, tx1f);
    prep_x<<<4096, 256, 0, stream>>>(x, xA, TX);
    transpose_to_bf16<<<dim3(8, 128), dim3(32, 8), 0, stream>>>(x, 4096, 200, xT, 256, 4096);
    transpose_to_bf16<<<dim3(128, 7), dim3(32, 8), 0, stream>>>(gglw, 200, 4096, gglwT, 4096, 224);

    // attr = sigmoid(x @ ggl_w + b)
    gemm_bt<<<dim3(32, 32), 256, 0, stream>>>(xA, gglwT, 224, 224, 224, MODE_ATTR,
                                              nullptr, attr, nullptr, gglb);
    rownorm<<<4096, 256, 0, stream>>>(attr, rninv);
    // adj = (attr @ attr^T) * rninv_i * rninv_j  (symmetric, mirrored writes)
    gemm_bt<<<dim3(32, 32), 256, 0, stream>>>(attr, attr, 4096, 4096, 4096, MODE_ADJ,
                                              adjf, nullptr, rninv, rninv);
    rowstats<<<4096, 256, 0, stream>>>(adjf, rmaxinv, dinv);
    anorm_w<<<dim3(64, 64), 256, 0, stream>>>(adjf, rmaxinv, dinv, adjf, W);

    const int txmode = slicepath ? MODE_TXS : MODE_TXP;
    const int nsl    = slicepath ? 8 : 1;
    float* tx1buf = slicepath ? txs : tx1f;
    float* tx2buf = slicepath ? txs : tx2f;
    // tx1 = M @ x  (split-K=8)
    gemm_bt<<<dim3(2, 32, 8), 256, 0, stream>>>(W, xT, 4096, 4096, 512, txmode,
                                                tx1buf, nullptr, nullptr, nullptr);
    tx_convert1<<<dim3(8, 128), dim3(32, 8), 0, stream>>>(tx1buf, nsl, TX, tx1T);
    // tx2 = 2*(M @ tx1) - x  (split-K=8)
    gemm_bt<<<dim3(2, 32, 8), 256, 0, stream>>>(W, tx1T, 4096, 4096, 512, txmode,
                                                tx2buf, nullptr, nullptr, nullptr);
    tx_convert2<<<3200, 256, 0, stream>>>(tx2buf, nsl, x, TX);
    // s_all = [tx0|tx1|tx2] @ Wall + bias_all
    gemm_bt<<<dim3(5, 32), 256, 0, stream>>>(TX, WallT, 608, 608, 608, MODE_SALL,
                                             sall, nullptr, nullptr, bias_all);
    bn_partial<<<dim3(10, 16), 256, 0, stream>>>(sall, colsum, colsq);
    bn_write<<<dim3(10, 16), 256, 0, stream>>>(sall, colsum, colsq, gamma, beta, out);
}

// Round 11
// 409.758 us; speedup vs baseline: 3.0793x; 1.1264x over previous
//
#include <hip/hip_runtime.h>
#include <stdint.h>

// MGCN pipeline, R11 (R10 neutral: symmetric adj halved MFMA work but the
// 64-lane scattered mirror store ate the win — MfmaUtil 15.6%, 181us).
// Changes vs R10:
//  1. Mirror write via padded-LDS transpose (mir[32][129]) -> coalesced
//     128-float row stores instead of 16-row x stride-4 scatter.
//  2. Triangular grid for adj (exactly 528 blocks, closed-form decode).
//  3. __launch_bounds__(256,3) -> 3 blocks/CU (528 co-resident in 1 round).
// Predicted: adj ~100us @ MfmaUtil ~40%; total ~380us.

typedef __attribute__((ext_vector_type(8))) short short8;
typedef __attribute__((ext_vector_type(4))) float floatx4;

__device__ __forceinline__ unsigned short f2bf(float f) {
    unsigned int x = __builtin_bit_cast(unsigned int, f);
    x += 0x7fffu + ((x >> 16) & 1u);   // RNE
    return (unsigned short)(x >> 16);
}

#define MODE_ATTR 0
#define MODE_ADJ  1   // symmetric: triangular grid, mirror via LDS transpose
#define MODE_TXS  3   // split-K partial: private slice write (no atomics)
#define MODE_TXP  2   // split-K partial: atomicAdd fallback
#define MODE_SALL 4

// ---------------------------------------------------------------------------
// Generic bt-GEMM: C[i][j] = sum_k A[i][k]*Bt[j][k], bf16 in, f32 accum.
// Block 256 thr = 4 waves in 2x2, each wave 64x64 (4x4 mfma tiles).
// Staging: global_load_lds w=16; LDS dst = wave-uniform base + lane*16.
// ---------------------------------------------------------------------------
__global__ __launch_bounds__(256, 3)
void gemm_bt(const unsigned short* __restrict__ A, const unsigned short* __restrict__ Bt,
             int lda, int ldb, int kchunk, int mode,
             float* __restrict__ fout, unsigned short* __restrict__ bout,
             const float* __restrict__ veci, const float* __restrict__ vecj)
{
    __shared__ __attribute__((aligned(16))) unsigned short As[128 * 32];
    __shared__ __attribute__((aligned(16))) unsigned short Bs[128 * 32];
    __shared__ float mir[32][129];   // mirror transpose staging (MODE_ADJ)

    int bx, by;
    if (mode == MODE_ADJ) {
        // triangular decode: block p -> (y, x>=y), row y starts at y*(65-y)/2
        int p = blockIdx.x;
        int y = (int)((65.0f - sqrtf(4225.0f - 8.0f * (float)p)) * 0.5f);
        while (y * (65 - y) / 2 > p) y--;
        while ((y + 1) * (64 - y) / 2 <= p) y++;
        by = y;
        bx = y + (p - y * (65 - y) / 2);
    } else {
        bx = blockIdx.x; by = blockIdx.y;
    }
    const int m0  = by * 128;
    const int n0  = bx * 128;
    const int t   = threadIdx.x;
    const int w   = t >> 6;
    const int q   = (t & 63) >> 4;
    const int m16 = t & 15;
    const int wm  = (w & 1) * 64;
    const int wn  = (w >> 1) * 64;
    const int kbeg = blockIdx.z * kchunk;
    const int kend = kbeg + kchunk;

    floatx4 acc[4][4];
#pragma unroll
    for (int a = 0; a < 4; a++)
#pragma unroll
        for (int b = 0; b < 4; b++)
            acc[a][b] = (floatx4){0.f, 0.f, 0.f, 0.f};

    for (int k0 = kbeg; k0 < kend; k0 += 32) {
        __syncthreads();   // prev iteration's LDS reads complete
#pragma unroll
        for (int c = 0; c < 2; c++) {
            const int off    = (c * 256 + t) * 16;   // byte offset in 8KB tile
            const int row    = off >> 6;             // 64 B per tile row
            const int colb   = off & 63;
            const int ldsoff = c * 4096 + w * 1024;  // wave-uniform base
            const unsigned short* ga = A + (size_t)(m0 + row) * lda + k0 + (colb >> 1);
            __builtin_amdgcn_global_load_lds(
                (const __attribute__((address_space(1))) unsigned int*)ga,
                (__attribute__((address_space(3))) unsigned int*)((char*)As + ldsoff),
                16, 0, 0);
            const unsigned short* gb = Bt + (size_t)(n0 + row) * ldb + k0 + (colb >> 1);
            __builtin_amdgcn_global_load_lds(
                (const __attribute__((address_space(1))) unsigned int*)gb,
                (__attribute__((address_space(3))) unsigned int*)((char*)Bs + ldsoff),
                16, 0, 0);
        }
        __syncthreads();   // vmcnt drained before barrier -> LDS valid

        short8 af[4], bf[4];
#pragma unroll
        for (int mt = 0; mt < 4; mt++)
            af[mt] = *reinterpret_cast<const short8*>(&As[(wm + mt * 16 + m16) * 32 + q * 8]);
#pragma unroll
        for (int nt = 0; nt < 4; nt++)
            bf[nt] = *reinterpret_cast<const short8*>(&Bs[(wn + nt * 16 + m16) * 32 + q * 8]);
#pragma unroll
        for (int mt = 0; mt < 4; mt++)
#pragma unroll
            for (int nt = 0; nt < 4; nt++)
                acc[mt][nt] = __builtin_amdgcn_mfma_f32_16x16x32_bf16(af[mt], bf[nt], acc[mt][nt], 0, 0, 0);
    }

    // epilogue: C/D layout col = lane&15, row = q*4 + reg
    if (mode == MODE_ADJ) {
        float vi[4][4], vjv[4];
#pragma unroll
        for (int mt = 0; mt < 4; mt++)
#pragma unroll
            for (int r = 0; r < 4; r++)
                vi[mt][r] = veci[m0 + wm + mt * 16 + q * 4 + r];
#pragma unroll
        for (int nt = 0; nt < 4; nt++)
            vjv[nt] = vecj[n0 + wn + nt * 16 + m16];
        // upper tile, coalesced
#pragma unroll
        for (int mt = 0; mt < 4; mt++)
#pragma unroll
            for (int nt = 0; nt < 4; nt++)
#pragma unroll
                for (int r = 0; r < 4; r++) {
                    const int i = m0 + wm + mt * 16 + q * 4 + r;
                    const int j = n0 + wn + nt * 16 + m16;
                    fout[(size_t)i * 4096 + j] = acc[mt][nt][r] * vi[mt][r] * vjv[nt];
                }
        // mirror tile via LDS transpose, coalesced rows
        if (n0 > m0) {
            const int lrow = (w >> 1) * 16 + m16;   // 0..31
#pragma unroll
            for (int nt = 0; nt < 4; nt++) {
                __syncthreads();
#pragma unroll
                for (int mt = 0; mt < 4; mt++)
#pragma unroll
                    for (int r = 0; r < 4; r++)
                        mir[lrow][wm + mt * 16 + q * 4 + r] =
                            acc[mt][nt][r] * vi[mt][r] * vjv[nt];
                __syncthreads();
#pragma unroll
                for (int s = 0; s < 16; s++) {
                    const int idx = s * 256 + t;
                    const int lr  = idx >> 7, lc = idx & 127;
                    const int jr  = n0 + nt * 16 + ((lr < 16) ? lr : (48 + lr));
                    fout[(size_t)jr * 4096 + m0 + lc] = mir[lr][lc];
                }
            }
        }
    } else {
#pragma unroll
        for (int mt = 0; mt < 4; mt++) {
#pragma unroll
            for (int nt = 0; nt < 4; nt++) {
#pragma unroll
                for (int r = 0; r < 4; r++) {
                    const int i = m0 + wm + mt * 16 + q * 4 + r;
                    const int j = n0 + wn + nt * 16 + m16;
                    float v = acc[mt][nt][r];
                    if (mode == MODE_ATTR) {
                        v += vecj[j];
                        v = 1.0f / (1.0f + __expf(-v));
                        bout[(size_t)i * 4096 + j] = f2bf(v);
                    } else if (mode == MODE_TXS) {
                        fout[(size_t)blockIdx.z * 1048576 + (size_t)i * 256 + j] = v;
                    } else if (mode == MODE_TXP) {
                        atomicAdd(&fout[(size_t)i * 256 + j], v);
                    } else { // MODE_SALL
                        fout[(size_t)i * 640 + j] = v + vecj[j];
                    }
                }
            }
        }
    }
}

// ---------------------------------------------------------------------------
// prep kernels (f32 inputs -> bf16 staging)
// ---------------------------------------------------------------------------
__global__ void prep_x(const float* __restrict__ x, unsigned short* __restrict__ xA,
                       unsigned short* __restrict__ TX) {
    const int i = blockIdx.x;
    const int t = threadIdx.x;
    if (t < 224) {
        float v = (t < 200) ? x[(size_t)i * 200 + t] : 0.f;
        unsigned short b = f2bf(v);
        xA[(size_t)i * 224 + t] = b;
        if (t < 200) TX[(size_t)i * 608 + t] = b;
    }
    if (t >= 224 && t < 232) TX[(size_t)i * 608 + 600 + (t - 224)] = 0;
}

// out[c][r] = in[r][c] (f32 -> bf16), zero pad to [outRows][ldo]
__global__ void transpose_to_bf16(const float* __restrict__ in, int R, int C,
                                  unsigned short* __restrict__ out, int outRows, int ldo) {
    __shared__ float tile[32][33];
    const int c0 = blockIdx.x * 32;
    const int r0 = blockIdx.y * 32;
    const int tx = threadIdx.x, ty = threadIdx.y;  // 32 x 8
    for (int s = 0; s < 32; s += 8) {
        int r = r0 + ty + s, c = c0 + tx;
        tile[ty + s][tx] = (r < R && c < C) ? in[(size_t)r * C + c] : 0.f;
    }
    __syncthreads();
    for (int s = 0; s < 32; s += 8) {
        int orow = c0 + ty + s;
        int ocol = r0 + tx;
        if (orow < outRows && ocol < ldo)
            out[(size_t)orow * ldo + ocol] = f2bf(tile[tx][ty + s]);
    }
}

__global__ void prep_misc(const float* __restrict__ w1, const float* __restrict__ b1,
                          const float* __restrict__ w2, const float* __restrict__ b2,
                          const float* __restrict__ w3, const float* __restrict__ b3,
                          unsigned short* __restrict__ WallT, float* __restrict__ bias_all,
                          float* __restrict__ colsum, float* __restrict__ colsq,
                          float* __restrict__ txf) {
    const int tid0 = blockIdx.x * 256 + threadIdx.x;
    const int stride = gridDim.x * 256;
    // WallT[n][k] = Wall[k][n]; flat k index valid across orders.
    for (int p = tid0; p < 640 * 608; p += stride) {
        int n = p / 608, k = p % 608;
        float v = 0.f;
        if (n < 200)      { if (k < 200) v = w1[k * 200 + n]; }
        else if (n < 400) { if (k < 400) v = w2[k * 200 + (n - 200)]; }
        else if (n < 600) { if (k < 600) v = w3[k * 200 + (n - 400)]; }
        WallT[p] = f2bf(v);
    }
    for (int p = tid0; p < 640; p += stride) {
        float v = 0.f;
        if (p < 200) v = b1[p];
        else if (p < 400) v = b2[p - 200];
        else if (p < 600) v = b3[p - 400];
        bias_all[p] = v;
        colsum[p] = 0.f;
        colsq[p] = 0.f;
    }
    // zero split-K atomic accumulators (fallback path; cheap)
    for (int p = tid0; p < 2 * 1048576; p += stride)
        txf[p] = 0.f;
}

// ---------------------------------------------------------------------------
// row reductions
// ---------------------------------------------------------------------------
__global__ void rownorm(const unsigned short* __restrict__ attr, float* __restrict__ rninv) {
    const int i = blockIdx.x, t = threadIdx.x;
    const uint4* p = reinterpret_cast<const uint4*>(attr + (size_t)i * 4096);
    float s = 0.f;
#pragma unroll
    for (int c = 0; c < 2; c++) {
        uint4 u = p[t + c * 256];
        unsigned int uu[4] = {u.x, u.y, u.z, u.w};
#pragma unroll
        for (int e = 0; e < 4; e++) {
            float lo = __builtin_bit_cast(float, uu[e] << 16);
            float hi = __builtin_bit_cast(float, uu[e] & 0xffff0000u);
            s += lo * lo + hi * hi;
        }
    }
    __shared__ float red[4];
    for (int off = 32; off > 0; off >>= 1) s += __shfl_down(s, off, 64);
    if ((t & 63) == 0) red[t >> 6] = s;
    __syncthreads();
    if (t == 0) {
        float tot = red[0] + red[1] + red[2] + red[3];
        rninv[i] = 1.0f / fmaxf(sqrtf(tot), 1e-8f);
    }
}

__global__ void rowstats(const float* __restrict__ adj, float* __restrict__ rmaxinv,
                         float* __restrict__ dinv) {
    const int i = blockIdx.x, t = threadIdx.x;
    const float4* p = reinterpret_cast<const float4*>(adj + (size_t)i * 4096);
    float sm = 0.f, mx = -3.4e38f;
#pragma unroll
    for (int c = 0; c < 4; c++) {
        float4 v = p[t + c * 256];
        sm += (v.x + v.y) + (v.z + v.w);
        mx = fmaxf(mx, fmaxf(fmaxf(v.x, v.y), fmaxf(v.z, v.w)));
    }
    __shared__ float rs[4], rm[4];
    for (int off = 32; off > 0; off >>= 1) {
        sm += __shfl_down(sm, off, 64);
        mx = fmaxf(mx, __shfl_down(mx, off, 64));
    }
    if ((t & 63) == 0) { rs[t >> 6] = sm; rm[t >> 6] = mx; }
    __syncthreads();
    if (t == 0) {
        float S = rs[0] + rs[1] + rs[2] + rs[3];
        float M = fmaxf(fmaxf(rm[0], rm[1]), fmaxf(rm[2], rm[3]));
        float diag = adj[(size_t)i * 4096 + i];
        float deg = (S - diag) / M;
        rmaxinv[i] = 1.0f / M;
        dinv[i] = (deg > 0.f) ? rsqrtf(deg) : 0.f;
    }
}

// A_norm (f32, IN PLACE over adj: same-thread RMW) + W[p][q] = -dinv_p*dinv_q*A0[q][p]
__global__ void anorm_w(const float* __restrict__ adj, const float* __restrict__ rmaxinv,
                        const float* __restrict__ dinv,
                        float* __restrict__ outA, unsigned short* __restrict__ W) {
    __shared__ float wt[64][65];
    const int j0 = blockIdx.x * 64, i0 = blockIdx.y * 64;
    const int tx = threadIdx.x & 63, ty = threadIdx.x >> 6;
    const int j = j0 + tx;
    const float dj = dinv[j];
#pragma unroll
    for (int s = 0; s < 64; s += 4) {
        int i = i0 + s + ty;
        float a = adj[(size_t)i * 4096 + j] * rmaxinv[i];
        outA[(size_t)i * 4096 + j] = a;
        wt[s + ty][tx] = (i == j) ? 0.f : (-dinv[i] * dj * a);
    }
    __syncthreads();
    const int icol = i0 + tx;
#pragma unroll
    for (int s = 0; s < 64; s += 4) {
        int jrow = j0 + s + ty;
        W[(size_t)jrow * 4096 + icol] = f2bf(wt[tx][s + ty]);
    }
}

// ---------------------------------------------------------------------------
// split-K converts (sum nslices slices of [4096][256])
// ---------------------------------------------------------------------------
__global__ void tx_convert1(const float* __restrict__ tf, int nslices,
                            unsigned short* __restrict__ TX,
                            unsigned short* __restrict__ tx1T) {
    __shared__ float tile[32][33];
    const int j0 = blockIdx.x * 32;
    const int i0 = blockIdx.y * 32;
    const int tx = threadIdx.x, ty = threadIdx.y;  // 32 x 8
    for (int s = 0; s < 32; s += 8) {
        int i = i0 + ty + s, j = j0 + tx;
        float v = 0.f;
        for (int z = 0; z < nslices; z++)
            v += tf[(size_t)z * 1048576 + (size_t)i * 256 + j];
        tile[ty + s][tx] = v;
        if (j < 200) TX[(size_t)i * 608 + 200 + j] = f2bf(v);
    }
    __syncthreads();
    for (int s = 0; s < 32; s += 8) {
        int jr = j0 + ty + s;
        int ic = i0 + tx;
        tx1T[(size_t)jr * 4096 + ic] = f2bf(tile[tx][ty + s]);
    }
}

__global__ void tx_convert2(const float* __restrict__ tf, int nslices,
                            const float* __restrict__ x,
                            unsigned short* __restrict__ TX) {
    int idx = blockIdx.x * 256 + threadIdx.x;
    if (idx >= 4096 * 200) return;
    int i = idx / 200, j = idx % 200;
    float v = 0.f;
    for (int z = 0; z < nslices; z++)
        v += tf[(size_t)z * 1048576 + (size_t)i * 256 + j];
    TX[(size_t)i * 608 + 400 + j] = f2bf(2.f * v - x[idx]);
}

// ---------------------------------------------------------------------------
// BatchNorm: two-phase column stats over 4096 rows, 600 cols
// ---------------------------------------------------------------------------
__global__ void bn_partial(const float* __restrict__ sall, float* __restrict__ colsum,
                           float* __restrict__ colsq) {
    const int tx = threadIdx.x & 63, ty = threadIdx.x >> 6;
    const int c = blockIdx.x * 64 + tx;
    const int r0 = blockIdx.y * 256;
    float sm = 0.f, sq = 0.f;
    if (c < 600) {
        for (int s = 0; s < 256; s += 4) {
            float v = sall[(size_t)(r0 + s + ty) * 640 + c];
            sm += v; sq += v * v;
        }
    }
    __shared__ float ls[4][64], lq[4][64];
    ls[ty][tx] = sm; lq[ty][tx] = sq;
    __syncthreads();
    if (ty == 0 && c < 600) {
        atomicAdd(&colsum[c], ls[0][tx] + ls[1][tx] + ls[2][tx] + ls[3][tx]);
        atomicAdd(&colsq[c], lq[0][tx] + lq[1][tx] + lq[2][tx] + lq[3][tx]);
    }
}

__global__ void bn_write(const float* __restrict__ sall, const float* __restrict__ colsum,
                         const float* __restrict__ colsq, const float* __restrict__ gamma,
                         const float* __restrict__ beta, float* __restrict__ out) {
    const int tx = threadIdx.x & 63, ty = threadIdx.x >> 6;
    const int c = blockIdx.x * 64 + tx;
    if (c >= 600) return;
    const float mu  = colsum[c] * (1.f / 4096.f);
    float var = colsq[c] * (1.f / 4096.f) - mu * mu;
    var = fmaxf(var, 0.f);
    const float inv = rsqrtf(var + 1e-5f);
    const int cc = c % 200;
    const float g = gamma[cc] * inv, be = beta[cc];
    const size_t base = (size_t)(c / 200) * 819200;
    const int r0 = blockIdx.y * 256;
    for (int s = 0; s < 256; s += 4) {
        int r = r0 + s + ty;
        float v = sall[(size_t)r * 640 + c];
        out[base + (size_t)r * 200 + cc] = g * (v - mu) + be;
    }
}

// ---------------------------------------------------------------------------
extern "C" void kernel_launch(void* const* d_in, const int* in_sizes, int n_in,
                              void* d_out, int out_size, void* d_ws, size_t ws_size,
                              hipStream_t stream) {
    const float* x     = (const float*)d_in[0];
    const float* gglw  = (const float*)d_in[1];
    const float* gglb  = (const float*)d_in[2];
    const float* w1    = (const float*)d_in[3];
    const float* b1    = (const float*)d_in[4];
    const float* w2    = (const float*)d_in[5];
    const float* b2    = (const float*)d_in[6];
    const float* w3    = (const float*)d_in[7];
    const float* b3    = (const float*)d_in[8];
    const float* gamma = (const float*)d_in[9];
    const float* beta  = (const float*)d_in[10];
    float* out = (float*)d_out;

    char* ws = (char*)d_ws;
    size_t off = 0;
    auto alloc = [&](size_t bytes) -> void* {
        void* p = ws + off;
        off += (bytes + 255) & ~(size_t)255;
        return p;
    };
    unsigned short* TX    = (unsigned short*)alloc(4096ull * 608 * 2);
    unsigned short* WallT = (unsigned short*)alloc(640ull * 608 * 2);
    float*          sall  = (float*)alloc(4096ull * 640 * 4);
    float* bias_all = (float*)alloc(640 * 4);
    float* colsum   = (float*)alloc(640 * 4);
    float* colsq    = (float*)alloc(640 * 4);
    unsigned short* xA    = (unsigned short*)alloc(4096ull * 224 * 2);
    unsigned short* gglwT = (unsigned short*)alloc(4096ull * 224 * 2);
    unsigned short* xT    = (unsigned short*)alloc(256ull * 4096 * 2);
    unsigned short* tx1T  = (unsigned short*)alloc(256ull * 4096 * 2);
    float* rninv    = (float*)alloc(4096 * 4);
    float* rmaxinv  = (float*)alloc(4096 * 4);
    float* dinv     = (float*)alloc(4096 * 4);
    unsigned short* attrW = (unsigned short*)alloc(4096ull * 4096 * 2);  // attr, then W
    unsigned short* attr  = attrW;
    unsigned short* W     = attrW;
    float* txs = (float*)alloc(8ull * 1048576 * 4);   // 32MB split-K slices
    const bool slicepath = (off <= ws_size);
    // d_out scratch: x1..x3 region dead until bn_write.
    float* tx1f = out;
    float* tx2f = out + 1048576;
    float* adjf = out + 2457600;       // A_norm slot (f32 4096x4096) as adj

    prep_misc<<<1024, 256, 0, stream>>>(w1, b1, w2, b2, w3, b3,
                                        WallT, bias_all, colsum, colsq, tx1f);
    prep_x<<<4096, 256, 0, stream>>>(x, xA, TX);
    transpose_to_bf16<<<dim3(8, 128), dim3(32, 8), 0, stream>>>(x, 4096, 200, xT, 256, 4096);
    transpose_to_bf16<<<dim3(128, 7), dim3(32, 8), 0, stream>>>(gglw, 200, 4096, gglwT, 4096, 224);

    // attr = sigmoid(x @ ggl_w + b)
    gemm_bt<<<dim3(32, 32), 256, 0, stream>>>(xA, gglwT, 224, 224, 224, MODE_ATTR,
                                              nullptr, attr, nullptr, gglb);
    rownorm<<<4096, 256, 0, stream>>>(attr, rninv);
    // adj = (attr @ attr^T) * rninv_i * rninv_j  (symmetric; 528 triangular blocks)
    gemm_bt<<<dim3(528, 1), 256, 0, stream>>>(attr, attr, 4096, 4096, 4096, MODE_ADJ,
                                              adjf, nullptr, rninv, rninv);
    rowstats<<<4096, 256, 0, stream>>>(adjf, rmaxinv, dinv);
    anorm_w<<<dim3(64, 64), 256, 0, stream>>>(adjf, rmaxinv, dinv, adjf, W);

    const int txmode = slicepath ? MODE_TXS : MODE_TXP;
    const int nsl    = slicepath ? 8 : 1;
    float* tx1buf = slicepath ? txs : tx1f;
    float* tx2buf = slicepath ? txs : tx2f;
    // tx1 = M @ x  (split-K=8)
    gemm_bt<<<dim3(2, 32, 8), 256, 0, stream>>>(W, xT, 4096, 4096, 512, txmode,
                                                tx1buf, nullptr, nullptr, nullptr);
    tx_convert1<<<dim3(8, 128), dim3(32, 8), 0, stream>>>(tx1buf, nsl, TX, tx1T);
    // tx2 = 2*(M @ tx1) - x  (split-K=8)
    gemm_bt<<<dim3(2, 32, 8), 256, 0, stream>>>(W, tx1T, 4096, 4096, 512, txmode,
                                                tx2buf, nullptr, nullptr, nullptr);
    tx_convert2<<<3200, 256, 0, stream>>>(tx2buf, nsl, x, TX);
    // s_all = [tx0|tx1|tx2] @ Wall + bias_all
    gemm_bt<<<dim3(5, 32), 256, 0, stream>>>(TX, WallT, 608, 608, 608, MODE_SALL,
                                             sall, nullptr, nullptr, bias_all);
    bn_partial<<<dim3(10, 16), 256, 0, stream>>>(sall, colsum, colsq);
    bn_write<<<dim3(10, 16), 256, 0, stream>>>(sall, colsum, colsq, gamma, beta, out);
}

// Round 12
// 377.968 us; speedup vs baseline: 3.3383x; 1.0841x over previous
//
#include <hip/hip_runtime.h>
#include <stdint.h>

// MGCN pipeline, R12 (R11: 409.8us; adj 115us @ 24.6% Mfma).
// Changes vs R11:
//  1. adj stored bf16 UPPER-TRIANGLE only (no mirror epilogue, no mir LDS).
//  2. rowstats fused into adj epilogue (shuffle-reduce + atomicAdd/atomicMax;
//     col-partials of off-diag blocks cover the unstored lower triangle).
//  3. anorm_w2 reads lower tiles transposed from upper storage via padded LDS.
//  4. rownorm fused into attr epilogue (sigmoid^2 row sums) + tiny finalize.
//  5. adjb(bf16, 32MB) aliases the txs slab (dead-before-reuse, sequential).
// Predicted: adj ~90us, total ~350us.

typedef __attribute__((ext_vector_type(8))) short short8;
typedef __attribute__((ext_vector_type(4))) float floatx4;

__device__ __forceinline__ unsigned short f2bf(float f) {
    unsigned int x = __builtin_bit_cast(unsigned int, f);
    x += 0x7fffu + ((x >> 16) & 1u);   // RNE
    return (unsigned short)(x >> 16);
}
__device__ __forceinline__ float bf2f(unsigned short u) {
    return __builtin_bit_cast(float, (unsigned int)u << 16);
}

#define MODE_ATTR 0
#define MODE_ADJ  1   // triangular grid, bf16 upper-triangle store, fused stats
#define MODE_TXS  3   // split-K partial: private slice write
#define MODE_SALL 4

// ---------------------------------------------------------------------------
// Generic bt-GEMM: C[i][j] = sum_k A[i][k]*Bt[j][k], bf16 in, f32 accum.
// Block 256 thr = 4 waves in 2x2, each wave 64x64 (4x4 mfma tiles).
// ---------------------------------------------------------------------------
__global__ __launch_bounds__(256, 3)
void gemm_bt(const unsigned short* __restrict__ A, const unsigned short* __restrict__ Bt,
             int lda, int ldb, int kchunk, int mode,
             float* __restrict__ fout, unsigned short* __restrict__ bout,
             const float* __restrict__ veci, const float* __restrict__ vecj,
             float* __restrict__ rsum, unsigned int* __restrict__ rmaxu)
{
    __shared__ __attribute__((aligned(16))) unsigned short As[128 * 32];
    __shared__ __attribute__((aligned(16))) unsigned short Bs[128 * 32];

    int bx, by;
    if (mode == MODE_ADJ) {
        // triangular decode: block p -> (y, x>=y)
        int p = blockIdx.x;
        int y = (int)((65.0f - sqrtf(4225.0f - 8.0f * (float)p)) * 0.5f);
        while (y * (65 - y) / 2 > p) y--;
        while ((y + 1) * (64 - y) / 2 <= p) y++;
        by = y;
        bx = y + (p - y * (65 - y) / 2);
    } else {
        bx = blockIdx.x; by = blockIdx.y;
    }
    const int m0  = by * 128;
    const int n0  = bx * 128;
    const int t   = threadIdx.x;
    const int w   = t >> 6;
    const int q   = (t & 63) >> 4;
    const int m16 = t & 15;
    const int wm  = (w & 1) * 64;
    const int wn  = (w >> 1) * 64;
    const int kbeg = blockIdx.z * kchunk;
    const int kend = kbeg + kchunk;

    floatx4 acc[4][4];
#pragma unroll
    for (int a = 0; a < 4; a++)
#pragma unroll
        for (int b = 0; b < 4; b++)
            acc[a][b] = (floatx4){0.f, 0.f, 0.f, 0.f};

    for (int k0 = kbeg; k0 < kend; k0 += 32) {
        __syncthreads();   // prev iteration's LDS reads complete
#pragma unroll
        for (int c = 0; c < 2; c++) {
            const int off    = (c * 256 + t) * 16;
            const int row    = off >> 6;
            const int colb   = off & 63;
            const int ldsoff = c * 4096 + w * 1024;
            const unsigned short* ga = A + (size_t)(m0 + row) * lda + k0 + (colb >> 1);
            __builtin_amdgcn_global_load_lds(
                (const __attribute__((address_space(1))) unsigned int*)ga,
                (__attribute__((address_space(3))) unsigned int*)((char*)As + ldsoff),
                16, 0, 0);
            const unsigned short* gb = Bt + (size_t)(n0 + row) * ldb + k0 + (colb >> 1);
            __builtin_amdgcn_global_load_lds(
                (const __attribute__((address_space(1))) unsigned int*)gb,
                (__attribute__((address_space(3))) unsigned int*)((char*)Bs + ldsoff),
                16, 0, 0);
        }
        __syncthreads();

        short8 af[4], bf[4];
#pragma unroll
        for (int mt = 0; mt < 4; mt++)
            af[mt] = *reinterpret_cast<const short8*>(&As[(wm + mt * 16 + m16) * 32 + q * 8]);
#pragma unroll
        for (int nt = 0; nt < 4; nt++)
            bf[nt] = *reinterpret_cast<const short8*>(&Bs[(wn + nt * 16 + m16) * 32 + q * 8]);
#pragma unroll
        for (int mt = 0; mt < 4; mt++)
#pragma unroll
            for (int nt = 0; nt < 4; nt++)
                acc[mt][nt] = __builtin_amdgcn_mfma_f32_16x16x32_bf16(af[mt], bf[nt], acc[mt][nt], 0, 0, 0);
    }

    // epilogue: C/D layout col = lane&15, row = q*4 + reg
    if (mode == MODE_ADJ) {
        float vi[4][4], vjv[4];
#pragma unroll
        for (int mt = 0; mt < 4; mt++)
#pragma unroll
            for (int r = 0; r < 4; r++)
                vi[mt][r] = veci[m0 + wm + mt * 16 + q * 4 + r];
#pragma unroll
        for (int nt = 0; nt < 4; nt++)
            vjv[nt] = vecj[n0 + wn + nt * 16 + m16];
        // bf16 store (upper-triangle block)
#pragma unroll
        for (int mt = 0; mt < 4; mt++)
#pragma unroll
            for (int nt = 0; nt < 4; nt++)
#pragma unroll
                for (int r = 0; r < 4; r++) {
                    const int i = m0 + wm + mt * 16 + q * 4 + r;
                    const int j = n0 + wn + nt * 16 + m16;
                    bout[(size_t)i * 4096 + j] = f2bf(acc[mt][nt][r] * vi[mt][r] * vjv[nt]);
                }
        // fused row stats (sum/max over this tile's 128 cols)
#pragma unroll
        for (int mt = 0; mt < 4; mt++)
#pragma unroll
            for (int r = 0; r < 4; r++) {
                float s = 0.f, mx = 0.f;
#pragma unroll
                for (int nt = 0; nt < 4; nt++) {
                    float b = acc[mt][nt][r] * vjv[nt];
                    s += b; mx = fmaxf(mx, b);
                }
                s += __shfl_xor(s, 1);  mx = fmaxf(mx, __shfl_xor(mx, 1));
                s += __shfl_xor(s, 2);  mx = fmaxf(mx, __shfl_xor(mx, 2));
                s += __shfl_xor(s, 4);  mx = fmaxf(mx, __shfl_xor(mx, 4));
                s += __shfl_xor(s, 8);  mx = fmaxf(mx, __shfl_xor(mx, 8));
                if (m16 == 0) {
                    const int i = m0 + wm + mt * 16 + q * 4 + r;
                    atomicAdd(&rsum[i], s * vi[mt][r]);
                    atomicMax(&rmaxu[i], __float_as_uint(mx * vi[mt][r]));
                }
            }
        // fused col stats: symmetric contribution of the unstored lower tile
        if (n0 > m0) {
#pragma unroll
            for (int nt = 0; nt < 4; nt++) {
                float s = 0.f, mx = 0.f;
#pragma unroll
                for (int mt = 0; mt < 4; mt++)
#pragma unroll
                    for (int r = 0; r < 4; r++) {
                        float b = acc[mt][nt][r] * vi[mt][r];
                        s += b; mx = fmaxf(mx, b);
                    }
                s += __shfl_xor(s, 16);  mx = fmaxf(mx, __shfl_xor(mx, 16));
                s += __shfl_xor(s, 32);  mx = fmaxf(mx, __shfl_xor(mx, 32));
                if (q == 0) {
                    const int j = n0 + wn + nt * 16 + m16;
                    atomicAdd(&rsum[j], s * vjv[nt]);
                    atomicMax(&rmaxu[j], __float_as_uint(mx * vjv[nt]));
                }
            }
        }
    } else if (mode == MODE_ATTR) {
#pragma unroll
        for (int mt = 0; mt < 4; mt++)
#pragma unroll
            for (int r = 0; r < 4; r++) {
                const int i = m0 + wm + mt * 16 + q * 4 + r;
                float s = 0.f;
#pragma unroll
                for (int nt = 0; nt < 4; nt++) {
                    const int j = n0 + wn + nt * 16 + m16;
                    float v = acc[mt][nt][r] + vecj[j];
                    v = 1.0f / (1.0f + __expf(-v));
                    bout[(size_t)i * 4096 + j] = f2bf(v);
                    s += v * v;
                }
                s += __shfl_xor(s, 1);
                s += __shfl_xor(s, 2);
                s += __shfl_xor(s, 4);
                s += __shfl_xor(s, 8);
                if (m16 == 0) atomicAdd(&rsum[i], s);
            }
    } else {
#pragma unroll
        for (int mt = 0; mt < 4; mt++)
#pragma unroll
            for (int nt = 0; nt < 4; nt++)
#pragma unroll
                for (int r = 0; r < 4; r++) {
                    const int i = m0 + wm + mt * 16 + q * 4 + r;
                    const int j = n0 + wn + nt * 16 + m16;
                    float v = acc[mt][nt][r];
                    if (mode == MODE_TXS)
                        fout[(size_t)blockIdx.z * 1048576 + (size_t)i * 256 + j] = v;
                    else   // MODE_SALL
                        fout[(size_t)i * 640 + j] = v + vecj[j];
                }
    }
}

// ---------------------------------------------------------------------------
// prep kernels
// ---------------------------------------------------------------------------
__global__ void prep_x(const float* __restrict__ x, unsigned short* __restrict__ xA,
                       unsigned short* __restrict__ TX) {
    const int i = blockIdx.x;
    const int t = threadIdx.x;
    if (t < 224) {
        float v = (t < 200) ? x[(size_t)i * 200 + t] : 0.f;
        unsigned short b = f2bf(v);
        xA[(size_t)i * 224 + t] = b;
        if (t < 200) TX[(size_t)i * 608 + t] = b;
    }
    if (t >= 224 && t < 232) TX[(size_t)i * 608 + 600 + (t - 224)] = 0;
}

__global__ void transpose_to_bf16(const float* __restrict__ in, int R, int C,
                                  unsigned short* __restrict__ out, int outRows, int ldo) {
    __shared__ float tile[32][33];
    const int c0 = blockIdx.x * 32;
    const int r0 = blockIdx.y * 32;
    const int tx = threadIdx.x, ty = threadIdx.y;  // 32 x 8
    for (int s = 0; s < 32; s += 8) {
        int r = r0 + ty + s, c = c0 + tx;
        tile[ty + s][tx] = (r < R && c < C) ? in[(size_t)r * C + c] : 0.f;
    }
    __syncthreads();
    for (int s = 0; s < 32; s += 8) {
        int orow = c0 + ty + s;
        int ocol = r0 + tx;
        if (orow < outRows && ocol < ldo)
            out[(size_t)orow * ldo + ocol] = f2bf(tile[tx][ty + s]);
    }
}

__global__ void prep_misc(const float* __restrict__ w1, const float* __restrict__ b1,
                          const float* __restrict__ w2, const float* __restrict__ b2,
                          const float* __restrict__ w3, const float* __restrict__ b3,
                          unsigned short* __restrict__ WallT, float* __restrict__ bias_all,
                          float* __restrict__ colsum, float* __restrict__ colsq,
                          float* __restrict__ rnsum, float* __restrict__ rowsum,
                          unsigned int* __restrict__ rowmaxu) {
    const int tid0 = blockIdx.x * 256 + threadIdx.x;
    const int stride = gridDim.x * 256;
    for (int p = tid0; p < 640 * 608; p += stride) {
        int n = p / 608, k = p % 608;
        float v = 0.f;
        if (n < 200)      { if (k < 200) v = w1[k * 200 + n]; }
        else if (n < 400) { if (k < 400) v = w2[k * 200 + (n - 200)]; }
        else if (n < 600) { if (k < 600) v = w3[k * 200 + (n - 400)]; }
        WallT[p] = f2bf(v);
    }
    for (int p = tid0; p < 640; p += stride) {
        float v = 0.f;
        if (p < 200) v = b1[p];
        else if (p < 400) v = b2[p - 200];
        else if (p < 600) v = b3[p - 400];
        bias_all[p] = v;
        colsum[p] = 0.f;
        colsq[p] = 0.f;
    }
    for (int p = tid0; p < 4096; p += stride) {
        rnsum[p] = 0.f;
        rowsum[p] = 0.f;
        rowmaxu[p] = 0u;
    }
}

// ---------------------------------------------------------------------------
// tiny finalizers
// ---------------------------------------------------------------------------
__global__ void finalize_rninv(const float* __restrict__ rnsum, float* __restrict__ rninv) {
    int i = blockIdx.x * 256 + threadIdx.x;
    if (i < 4096) rninv[i] = 1.0f / fmaxf(sqrtf(rnsum[i]), 1e-8f);
}

__global__ void dinv_finalize(const unsigned short* __restrict__ adjb,
                              const float* __restrict__ rowsum,
                              const unsigned int* __restrict__ rowmaxu,
                              float* __restrict__ rmaxinv, float* __restrict__ dinv) {
    int i = blockIdx.x * 256 + threadIdx.x;
    if (i >= 4096) return;
    float M = __uint_as_float(rowmaxu[i]);
    float diag = bf2f(adjb[(size_t)i * 4097]);
    float deg = (rowsum[i] - diag) / M;
    rmaxinv[i] = 1.0f / M;
    dinv[i] = (deg > 0.f) ? rsqrtf(deg) : 0.f;
}

// ---------------------------------------------------------------------------
// A_norm + W from bf16 upper-triangle adj.  Tile 64x64; lower-block tiles
// read the transposed upper tile through padded LDS.
// ---------------------------------------------------------------------------
__global__ void anorm_w2(const unsigned short* __restrict__ adjb,
                         const float* __restrict__ rmaxinv, const float* __restrict__ dinv,
                         float* __restrict__ An, unsigned short* __restrict__ W) {
    __shared__ float td[64][65];
    const int i0 = blockIdx.y * 64, j0 = blockIdx.x * 64;
    const int tx = threadIdx.x & 63, ty = threadIdx.x >> 6;
    if ((j0 >> 7) >= (i0 >> 7)) {
        // stored directly: adj[i][j] at adjb[i][j]
        const float dj = dinv[j0 + tx];
#pragma unroll
        for (int s = 0; s < 64; s += 4) {
            int i = i0 + s + ty;
            float a = bf2f(adjb[(size_t)i * 4096 + j0 + tx]) * rmaxinv[i];
            An[(size_t)i * 4096 + j0 + tx] = a;
            td[s + ty][tx] = (i == j0 + tx) ? 0.f : (-dinv[i] * dj * a);
        }
        __syncthreads();
#pragma unroll
        for (int s = 0; s < 64; s += 4) {
            int jr = j0 + s + ty;
            W[(size_t)jr * 4096 + i0 + tx] = f2bf(td[tx][s + ty]);
        }
    } else {
        // lower block: adj[i][j] = adjb[j][i]
#pragma unroll
        for (int s = 0; s < 64; s += 4) {
            int jr = j0 + s + ty;
            td[s + ty][tx] = bf2f(adjb[(size_t)jr * 4096 + i0 + tx]);
        }
        __syncthreads();
#pragma unroll
        for (int s = 0; s < 64; s += 4) {
            int i = i0 + s + ty;
            An[(size_t)i * 4096 + j0 + tx] = td[tx][s + ty] * rmaxinv[i];
        }
        const float di = dinv[i0 + tx], rmi = rmaxinv[i0 + tx];
#pragma unroll
        for (int s = 0; s < 64; s += 4) {
            int jr = j0 + s + ty;
            W[(size_t)jr * 4096 + i0 + tx] = f2bf(-dinv[jr] * di * td[s + ty][tx] * rmi);
        }
    }
}

// ---------------------------------------------------------------------------
// split-K converts (sum 8 slices of [4096][256])
// ---------------------------------------------------------------------------
__global__ void tx_convert1(const float* __restrict__ tf, int nslices,
                            unsigned short* __restrict__ TX,
                            unsigned short* __restrict__ tx1T) {
    __shared__ float tile[32][33];
    const int j0 = blockIdx.x * 32;
    const int i0 = blockIdx.y * 32;
    const int tx = threadIdx.x, ty = threadIdx.y;  // 32 x 8
    for (int s = 0; s < 32; s += 8) {
        int i = i0 + ty + s, j = j0 + tx;
        float v = 0.f;
        for (int z = 0; z < nslices; z++)
            v += tf[(size_t)z * 1048576 + (size_t)i * 256 + j];
        tile[ty + s][tx] = v;
        if (j < 200) TX[(size_t)i * 608 + 200 + j] = f2bf(v);
    }
    __syncthreads();
    for (int s = 0; s < 32; s += 8) {
        int jr = j0 + ty + s;
        int ic = i0 + tx;
        tx1T[(size_t)jr * 4096 + ic] = f2bf(tile[tx][ty + s]);
    }
}

__global__ void tx_convert2(const float* __restrict__ tf, int nslices,
                            const float* __restrict__ x,
                            unsigned short* __restrict__ TX) {
    int idx = blockIdx.x * 256 + threadIdx.x;
    if (idx >= 4096 * 200) return;
    int i = idx / 200, j = idx % 200;
    float v = 0.f;
    for (int z = 0; z < nslices; z++)
        v += tf[(size_t)z * 1048576 + (size_t)i * 256 + j];
    TX[(size_t)i * 608 + 400 + j] = f2bf(2.f * v - x[idx]);
}

// ---------------------------------------------------------------------------
// BatchNorm
// ---------------------------------------------------------------------------
__global__ void bn_partial(const float* __restrict__ sall, float* __restrict__ colsum,
                           float* __restrict__ colsq) {
    const int tx = threadIdx.x & 63, ty = threadIdx.x >> 6;
    const int c = blockIdx.x * 64 + tx;
    const int r0 = blockIdx.y * 256;
    float sm = 0.f, sq = 0.f;
    if (c < 600) {
        for (int s = 0; s < 256; s += 4) {
            float v = sall[(size_t)(r0 + s + ty) * 640 + c];
            sm += v; sq += v * v;
        }
    }
    __shared__ float ls[4][64], lq[4][64];
    ls[ty][tx] = sm; lq[ty][tx] = sq;
    __syncthreads();
    if (ty == 0 && c < 600) {
        atomicAdd(&colsum[c], ls[0][tx] + ls[1][tx] + ls[2][tx] + ls[3][tx]);
        atomicAdd(&colsq[c], lq[0][tx] + lq[1][tx] + lq[2][tx] + lq[3][tx]);
    }
}

__global__ void bn_write(const float* __restrict__ sall, const float* __restrict__ colsum,
                         const float* __restrict__ colsq, const float* __restrict__ gamma,
                         const float* __restrict__ beta, float* __restrict__ out) {
    const int tx = threadIdx.x & 63, ty = threadIdx.x >> 6;
    const int c = blockIdx.x * 64 + tx;
    if (c >= 600) return;
    const float mu  = colsum[c] * (1.f / 4096.f);
    float var = colsq[c] * (1.f / 4096.f) - mu * mu;
    var = fmaxf(var, 0.f);
    const float inv = rsqrtf(var + 1e-5f);
    const int cc = c % 200;
    const float g = gamma[cc] * inv, be = beta[cc];
    const size_t base = (size_t)(c / 200) * 819200;
    const int r0 = blockIdx.y * 256;
    for (int s = 0; s < 256; s += 4) {
        int r = r0 + s + ty;
        float v = sall[(size_t)r * 640 + c];
        out[base + (size_t)r * 200 + cc] = g * (v - mu) + be;
    }
}

// ---------------------------------------------------------------------------
extern "C" void kernel_launch(void* const* d_in, const int* in_sizes, int n_in,
                              void* d_out, int out_size, void* d_ws, size_t ws_size,
                              hipStream_t stream) {
    const float* x     = (const float*)d_in[0];
    const float* gglw  = (const float*)d_in[1];
    const float* gglb  = (const float*)d_in[2];
    const float* w1    = (const float*)d_in[3];
    const float* b1    = (const float*)d_in[4];
    const float* w2    = (const float*)d_in[5];
    const float* b2    = (const float*)d_in[6];
    const float* w3    = (const float*)d_in[7];
    const float* b3    = (const float*)d_in[8];
    const float* gamma = (const float*)d_in[9];
    const float* beta  = (const float*)d_in[10];
    float* out = (float*)d_out;

    char* ws = (char*)d_ws;
    size_t off = 0;
    auto alloc = [&](size_t bytes) -> void* {
        void* p = ws + off;
        off += (bytes + 255) & ~(size_t)255;
        return p;
    };
    unsigned short* TX    = (unsigned short*)alloc(4096ull * 608 * 2);
    unsigned short* WallT = (unsigned short*)alloc(640ull * 608 * 2);
    float*          sall  = (float*)alloc(4096ull * 640 * 4);
    float* bias_all = (float*)alloc(640 * 4);
    float* colsum   = (float*)alloc(640 * 4);
    float* colsq    = (float*)alloc(640 * 4);
    float* rnsum    = (float*)alloc(4096 * 4);
    float* rowsum   = (float*)alloc(4096 * 4);
    unsigned int* rowmaxu = (unsigned int*)alloc(4096 * 4);
    unsigned short* xA    = (unsigned short*)alloc(4096ull * 224 * 2);
    unsigned short* gglwT = (unsigned short*)alloc(4096ull * 224 * 2);
    unsigned short* xT    = (unsigned short*)alloc(256ull * 4096 * 2);
    unsigned short* tx1T  = (unsigned short*)alloc(256ull * 4096 * 2);
    float* rninv    = (float*)alloc(4096 * 4);
    float* rmaxinv  = (float*)alloc(4096 * 4);
    float* dinv     = (float*)alloc(4096 * 4);
    unsigned short* attrW = (unsigned short*)alloc(4096ull * 4096 * 2);  // attr, then W
    unsigned short* attr  = attrW;
    unsigned short* W     = attrW;
    float* txs = (float*)alloc(8ull * 1048576 * 4);       // 32MB: adjb, then slices
    unsigned short* adjb = (unsigned short*)txs;          // bf16 4096x4096, upper blocks
    // ws total ~95 MB (R1/R3 evidence: ws >= ~125 MB)
    float* adjAn = out + 2457600;      // A_norm f32 slot in d_out

    prep_misc<<<1024, 256, 0, stream>>>(w1, b1, w2, b2, w3, b3,
                                        WallT, bias_all, colsum, colsq,
                                        rnsum, rowsum, rowmaxu);
    prep_x<<<4096, 256, 0, stream>>>(x, xA, TX);
    transpose_to_bf16<<<dim3(8, 128), dim3(32, 8), 0, stream>>>(x, 4096, 200, xT, 256, 4096);
    transpose_to_bf16<<<dim3(128, 7), dim3(32, 8), 0, stream>>>(gglw, 200, 4096, gglwT, 4096, 224);

    // attr = sigmoid(x @ ggl_w + b), fused row-norm partials
    gemm_bt<<<dim3(32, 32), 256, 0, stream>>>(xA, gglwT, 224, 224, 224, MODE_ATTR,
                                              nullptr, attr, nullptr, gglb, rnsum, nullptr);
    finalize_rninv<<<16, 256, 0, stream>>>(rnsum, rninv);
    // adj upper triangle (bf16) + fused row/col stats
    gemm_bt<<<dim3(528, 1), 256, 0, stream>>>(attr, attr, 4096, 4096, 4096, MODE_ADJ,
                                              nullptr, adjb, rninv, rninv, rowsum, rowmaxu);
    dinv_finalize<<<16, 256, 0, stream>>>(adjb, rowsum, rowmaxu, rmaxinv, dinv);
    // A_norm (f32 output slot) + W (bf16, attr slab)
    anorm_w2<<<dim3(64, 64), 256, 0, stream>>>(adjb, rmaxinv, dinv, adjAn, W);

    // tx1 = M @ x  (split-K=8 into txs slices; adjb is dead now)
    gemm_bt<<<dim3(2, 32, 8), 256, 0, stream>>>(W, xT, 4096, 4096, 512, MODE_TXS,
                                                txs, nullptr, nullptr, nullptr, nullptr, nullptr);
    tx_convert1<<<dim3(8, 128), dim3(32, 8), 0, stream>>>(txs, 8, TX, tx1T);
    // tx2 = 2*(M @ tx1) - x
    gemm_bt<<<dim3(2, 32, 8), 256, 0, stream>>>(W, tx1T, 4096, 4096, 512, MODE_TXS,
                                                txs, nullptr, nullptr, nullptr, nullptr, nullptr);
    tx_convert2<<<3200, 256, 0, stream>>>(txs, 8, x, TX);
    // s_all = [tx0|tx1|tx2] @ Wall + bias_all
    gemm_bt<<<dim3(5, 32), 256, 0, stream>>>(TX, WallT, 608, 608, 608, MODE_SALL,
                                             sall, nullptr, nullptr, bias_all, nullptr, nullptr);
    bn_partial<<<dim3(10, 16), 256, 0, stream>>>(sall, colsum, colsq);
    bn_write<<<dim3(10, 16), 256, 0, stream>>>(sall, colsum, colsq, gamma, beta, out);
}